// Round 1
// baseline (201.517 us; speedup 1.0000x reference)
//
#include <hip/hip_runtime.h>

#define DEVINL __device__ __forceinline__

typedef __attribute__((ext_vector_type(8))) short bf8v;           // 8 bf16 bit-patterns (MFMA operand)
typedef __attribute__((ext_vector_type(4))) float f32x4;
typedef __attribute__((ext_vector_type(8))) unsigned short us8;
typedef __attribute__((ext_vector_type(4))) unsigned short us4;

DEVINL unsigned short f2bf(float f) {                 // round-to-nearest-even fp32->bf16
  unsigned int u = __builtin_bit_cast(unsigned int, f);
  u += 0x7fffu + ((u >> 16) & 1u);
  return (unsigned short)(u >> 16);
}
DEVINL float bf2f(unsigned short h) {
  unsigned int u = ((unsigned int)h) << 16;
  return __builtin_bit_cast(float, u);
}

// ------------------------------------------------------------------
// Generic TN GEMM: C[m,n] = sum_k A[m,k]*B[n,k].  A,B bf16 (optionally
// split hi/lo: PASSES==3 computes hh + hl + lh).  Tile 128x128, BK=64,
// 256 threads = 4 waves in 2x2, each wave 4x4 frags of 16x16x32 MFMA.
// grid.z decodes (z2,z1) with z1count; per-z offsets via aS/bS/cS.
// LDS rows padded to 72 shorts (144B) -> bank-uniform b128 read/write.
// ------------------------------------------------------------------
template<int PASSES, bool OUT_BF16>
__global__ __launch_bounds__(256, 2)
void gemm_tn(const unsigned short* __restrict__ Ahi, const unsigned short* __restrict__ Alo,
             const unsigned short* __restrict__ Bhi, const unsigned short* __restrict__ Blo,
             void* __restrict__ Cout,
             int lda, int ldb, int ldc, int ksteps, int z1count,
             long aS1, long aS2, long bS1, long bS2, long cS1, long cS2)
{
  __shared__ __align__(16) unsigned short smem[(PASSES == 3 ? 4 : 2) * 128 * 72];
  unsigned short* As_hi = smem;
  unsigned short* Bs_hi = smem + 128 * 72;
  unsigned short* As_lo = smem + 2 * 128 * 72;  // only used if PASSES==3
  unsigned short* Bs_lo = smem + 3 * 128 * 72;

  const int t = threadIdx.x;
  const int lane = t & 63;
  const int wave = t >> 6;
  const int wm = wave >> 1, wn = wave & 1;
  const int lr = lane & 15, lk = lane >> 4;

  const int z = blockIdx.z;
  const int zb = z / z1count, z1 = z - zb * z1count;
  const unsigned short* Ah = Ahi + zb * aS2 + z1 * aS1;
  const unsigned short* Bh = Bhi + zb * bS2 + z1 * bS1;
  const unsigned short* Al = (PASSES == 3) ? (Alo + zb * aS2 + z1 * aS1) : nullptr;
  const unsigned short* Bl = (PASSES == 3) ? (Blo + zb * bS2 + z1 * bS1) : nullptr;
  const long cOff = zb * cS2 + z1 * cS1;

  const int mbase = blockIdx.y * 128;
  const int nbase = blockIdx.x * 128;

  f32x4 acc[4][4];
#pragma unroll
  for (int i = 0; i < 4; ++i)
#pragma unroll
    for (int j = 0; j < 4; ++j) acc[i][j] = (f32x4)0.0f;

  for (int kt = 0; kt < ksteps; ++kt) {
    const int k0 = kt * 64;
#pragma unroll
    for (int i = 0; i < 4; ++i) {
      const int q = i * 256 + t;
      const int row = q >> 3, c = q & 7;
      const int lo = row * 72 + c * 8;
      *(us8*)&As_hi[lo] = *(const us8*)&Ah[(long)(mbase + row) * lda + k0 + c * 8];
      *(us8*)&Bs_hi[lo] = *(const us8*)&Bh[(long)(nbase + row) * ldb + k0 + c * 8];
      if (PASSES == 3) {
        *(us8*)&As_lo[lo] = *(const us8*)&Al[(long)(mbase + row) * lda + k0 + c * 8];
        *(us8*)&Bs_lo[lo] = *(const us8*)&Bl[(long)(nbase + row) * ldb + k0 + c * 8];
      }
    }
    __syncthreads();
#pragma unroll
    for (int ks = 0; ks < 2; ++ks) {
      const int ko = ks * 32 + lk * 8;
      bf8v ah[4], bh[4], al[4], bl[4];
#pragma unroll
      for (int mi = 0; mi < 4; ++mi) {
        const int r = (wm * 64 + mi * 16 + lr) * 72 + ko;
        ah[mi] = *(const bf8v*)&As_hi[r];
        if (PASSES == 3) al[mi] = *(const bf8v*)&As_lo[r];
      }
#pragma unroll
      for (int ni = 0; ni < 4; ++ni) {
        const int r = (wn * 64 + ni * 16 + lr) * 72 + ko;
        bh[ni] = *(const bf8v*)&Bs_hi[r];
        if (PASSES == 3) bl[ni] = *(const bf8v*)&Bs_lo[r];
      }
#pragma unroll
      for (int mi = 0; mi < 4; ++mi)
#pragma unroll
        for (int ni = 0; ni < 4; ++ni) {
          acc[mi][ni] = __builtin_amdgcn_mfma_f32_16x16x32_bf16(ah[mi], bh[ni], acc[mi][ni], 0, 0, 0);
          if (PASSES == 3) {
            acc[mi][ni] = __builtin_amdgcn_mfma_f32_16x16x32_bf16(ah[mi], bl[ni], acc[mi][ni], 0, 0, 0);
            acc[mi][ni] = __builtin_amdgcn_mfma_f32_16x16x32_bf16(al[mi], bh[ni], acc[mi][ni], 0, 0, 0);
          }
        }
    }
    __syncthreads();
  }

  // epilogue: D row=(lane>>4)*4+reg, col=lane&15 (m89-verified)
#pragma unroll
  for (int mi = 0; mi < 4; ++mi)
#pragma unroll
    for (int ni = 0; ni < 4; ++ni)
#pragma unroll
      for (int r = 0; r < 4; ++r) {
        const int gm = mbase + wm * 64 + mi * 16 + lk * 4 + r;
        const int gn = nbase + wn * 64 + ni * 16 + lr;
        const float v = acc[mi][ni][r];
        if (OUT_BF16) ((unsigned short*)Cout)[cOff + (long)gm * ldc + gn] = f2bf(v);
        else          ((float*)Cout)[cOff + (long)gm * ldc + gn] = v;
      }
}

// ------------------------------------------------------------------
// weights: theta/phi -> hi/lo split [256][256]; g -> bf16 [128][256];
// W2 -> bf16 [256][128]
// ------------------------------------------------------------------
__global__ __launch_bounds__(256)
void prep_weights(const float* __restrict__ g_w, const float* __restrict__ th_w,
                  const float* __restrict__ ph_w, const float* __restrict__ W_w,
                  unsigned short* __restrict__ whi, unsigned short* __restrict__ wlo,
                  unsigned short* __restrict__ wgh, unsigned short* __restrict__ w2h)
{
  const int i = blockIdx.x * 256 + threadIdx.x;  // [0, 65536)
  {
    const float v = (i < 32768) ? th_w[i] : ph_w[i - 32768];
    const unsigned short h = f2bf(v);
    whi[i] = h;
    wlo[i] = f2bf(v - bf2f(h));
  }
  if (i < 32768) {
    wgh[i] = f2bf(g_w[i]);
    w2h[i] = f2bf(W_w[i]);
  }
}

// ------------------------------------------------------------------
// x [b,c,n] fp32 -> xT hi/lo [b,n,c] bf16 (64x64 LDS tile transpose)
// ------------------------------------------------------------------
__global__ __launch_bounds__(256)
void transpose_split_x(const float* __restrict__ x,
                       unsigned short* __restrict__ xT_hi, unsigned short* __restrict__ xT_lo)
{
  __shared__ float T[64][65];
  const int b = blockIdx.z, c0 = blockIdx.y * 64, n0 = blockIdx.x * 64;
  const int t = threadIdx.x;
  const int cl = t >> 2, q = t & 3;
  const float* src = x + ((long)(b * 256 + c0 + cl)) * 4096 + n0 + q * 16;
#pragma unroll
  for (int j = 0; j < 4; ++j) {
    f32x4 v = *(const f32x4*)&src[j * 4];
#pragma unroll
    for (int e = 0; e < 4; ++e) T[q * 16 + j * 4 + e][cl] = v[e];
  }
  __syncthreads();
  const int nl = t >> 2;
  const long obase = ((long)b * 4096 + n0 + nl) * 256 + c0 + q * 16;
#pragma unroll
  for (int h = 0; h < 2; ++h) {
    us8 hi, lo;
#pragma unroll
    for (int e = 0; e < 8; ++e) {
      const float v = T[nl][q * 16 + h * 8 + e];
      const unsigned short hb = f2bf(v);
      hi[e] = hb;
      lo[e] = f2bf(v - bf2f(hb));
    }
    *(us8*)&xT_hi[obase + h * 8] = hi;
    *(us8*)&xT_lo[obase + h * 8] = lo;
  }
}

// ------------------------------------------------------------------
// per-row instance-norm + relu + hi/lo split for theta/phi rows
// z_all [b][384][4096]; rows 0..255 -> znorm hi/lo [b][256][4096]
// ------------------------------------------------------------------
__global__ __launch_bounds__(256)
void norm_split(const float* __restrict__ z,
                unsigned short* __restrict__ nhi, unsigned short* __restrict__ nlo)
{
  const int row = blockIdx.x;            // b*256 + m
  const int b = row >> 8, m = row & 255;
  const float* src = z + ((long)b * 384 + m) * 4096;
  const int t = threadIdx.x;
  f32x4 v[4];
  float s = 0.f, ss = 0.f;
#pragma unroll
  for (int i = 0; i < 4; ++i) {
    v[i] = *(const f32x4*)&src[i * 1024 + t * 4];
#pragma unroll
    for (int e = 0; e < 4; ++e) { s += v[i][e]; ss += v[i][e] * v[i][e]; }
  }
  __shared__ float r0[256], r1[256];
  r0[t] = s; r1[t] = ss;
  __syncthreads();
  for (int o = 128; o > 0; o >>= 1) {
    if (t < o) { r0[t] += r0[t + o]; r1[t] += r1[t + o]; }
    __syncthreads();
  }
  const float mean = r0[0] * (1.f / 4096.f);
  const float var = r1[0] * (1.f / 4096.f) - mean * mean;
  const float rs = rsqrtf(fmaxf(var, 0.f) + 1e-5f);
  const long obase = (long)row * 4096;
#pragma unroll
  for (int i = 0; i < 4; ++i) {
    us4 hi, lo;
#pragma unroll
    for (int e = 0; e < 4; ++e) {
      const float nv = fmaxf((v[i][e] - mean) * rs, 0.f);
      const unsigned short h = f2bf(nv);
      hi[e] = h;
      lo[e] = f2bf(nv - bf2f(h));
    }
    *(us4*)&nhi[obase + i * 1024 + t * 4] = hi;
    *(us4*)&nlo[obase + i * 1024 + t * 4] = lo;
  }
}

// ------------------------------------------------------------------
// stats for g rows (z_all rows 256..383): mean + rsig per (b,j)
// ------------------------------------------------------------------
__global__ __launch_bounds__(256)
void stats_g(const float* __restrict__ z, float* __restrict__ statsg)
{
  const int row = blockIdx.x;            // b*128 + j
  const int b = row >> 7, j = row & 127;
  const float* src = z + ((long)b * 384 + 256 + j) * 4096;
  const int t = threadIdx.x;
  float s = 0.f, ss = 0.f;
#pragma unroll
  for (int i = 0; i < 4; ++i) {
    f32x4 v = *(const f32x4*)&src[i * 1024 + t * 4];
#pragma unroll
    for (int e = 0; e < 4; ++e) { s += v[e]; ss += v[e] * v[e]; }
  }
  __shared__ float r0[256], r1[256];
  r0[t] = s; r1[t] = ss;
  __syncthreads();
  for (int o = 128; o > 0; o >>= 1) {
    if (t < o) { r0[t] += r0[t + o]; r1[t] += r1[t + o]; }
    __syncthreads();
  }
  if (t == 0) {
    const float mean = r0[0] * (1.f / 4096.f);
    const float var = r1[0] * (1.f / 4096.f) - mean * mean;
    statsg[row * 2] = mean;
    statsg[row * 2 + 1] = rsqrtf(fmaxf(var, 0.f) + 1e-5f);
  }
}

// ------------------------------------------------------------------
// normalize + relu + transpose g: z rows 256..383 -> gT [b][n][128] bf16
// ------------------------------------------------------------------
__global__ __launch_bounds__(256)
void norm_transpose_g(const float* __restrict__ z, const float* __restrict__ statsg,
                      unsigned short* __restrict__ gT)
{
  __shared__ unsigned short T[64 * 136];
  const int b = blockIdx.y, n0 = blockIdx.x * 64;
  const int t = threadIdx.x;
  const int c = t >> 1, part = t & 1;
  const float mu = statsg[(b * 128 + c) * 2];
  const float rs = statsg[(b * 128 + c) * 2 + 1];
  const float* src = z + ((long)b * 384 + 256 + c) * 4096 + n0 + part * 32;
#pragma unroll
  for (int j = 0; j < 8; ++j) {
    f32x4 v = *(const f32x4*)&src[j * 4];
#pragma unroll
    for (int e = 0; e < 4; ++e) {
      const float nv = fmaxf((v[e] - mu) * rs, 0.f);
      T[(part * 32 + j * 4 + e) * 136 + c] = f2bf(nv);
    }
  }
  __syncthreads();
  const int nl = t >> 2, q = t & 3;
  const long obase = ((long)b * 4096 + n0 + nl) * 128 + q * 32;
#pragma unroll
  for (int k = 0; k < 4; ++k) {
    us8 o;
#pragma unroll
    for (int e = 0; e < 8; ++e) o[e] = T[nl * 136 + q * 32 + k * 8 + e];
    *(us8*)&gT[obase + k * 8] = o;
  }
}

// ------------------------------------------------------------------
// softmax over j: sums 8 deterministic K-split partials, writes attn bf16
// ------------------------------------------------------------------
__global__ __launch_bounds__(64)
void softmax_attn(const float* __restrict__ fpart, unsigned short* __restrict__ attn)
{
  const int row = blockIdx.x;            // b*128 + i
  const int b = row >> 7, i = row & 127;
  const int t = threadIdx.x;
  float v0 = 0.f, v1 = 0.f;
#pragma unroll
  for (int kc = 0; kc < 8; ++kc) {
    const float* p = fpart + ((long)(b * 8 + kc)) * 16384 + i * 128;
    v0 += p[t];
    v1 += p[t + 64];
  }
  float mx = fmaxf(v0, v1);
  for (int o = 32; o > 0; o >>= 1) mx = fmaxf(mx, __shfl_xor(mx, o));
  const float e0 = __expf(v0 - mx), e1 = __expf(v1 - mx);
  float s = e0 + e1;
  for (int o = 32; o > 0; o >>= 1) s += __shfl_xor(s, o);
  const float inv = 1.f / s;
  attn[(long)row * 128 + t] = f2bf(e0 * inv);
  attn[(long)row * 128 + t + 64] = f2bf(e1 * inv);
}

// ------------------------------------------------------------------
// final: per-row instance-norm of z2 (in d_out) + residual x, in place
// ------------------------------------------------------------------
__global__ __launch_bounds__(256)
void finalize(float* __restrict__ out, const float* __restrict__ x)
{
  const int row = blockIdx.x;            // b*256 + o
  const long base = (long)row * 4096;
  const int t = threadIdx.x;
  f32x4 v[4];
  float s = 0.f, ss = 0.f;
#pragma unroll
  for (int i = 0; i < 4; ++i) {
    v[i] = *(const f32x4*)&out[base + i * 1024 + t * 4];
#pragma unroll
    for (int e = 0; e < 4; ++e) { s += v[i][e]; ss += v[i][e] * v[i][e]; }
  }
  __shared__ float r0[256], r1[256];
  r0[t] = s; r1[t] = ss;
  __syncthreads();
  for (int o = 128; o > 0; o >>= 1) {
    if (t < o) { r0[t] += r0[t + o]; r1[t] += r1[t + o]; }
    __syncthreads();
  }
  const float mean = r0[0] * (1.f / 4096.f);
  const float var = r1[0] * (1.f / 4096.f) - mean * mean;
  const float rs = rsqrtf(fmaxf(var, 0.f) + 1e-5f);
#pragma unroll
  for (int i = 0; i < 4; ++i) {
    f32x4 xr = *(const f32x4*)&x[base + i * 1024 + t * 4];
    f32x4 o;
#pragma unroll
    for (int e = 0; e < 4; ++e) o[e] = (v[i][e] - mean) * rs + xr[e];
    *(f32x4*)&out[base + i * 1024 + t * 4] = o;
  }
}

// ------------------------------------------------------------------
extern "C" void kernel_launch(void* const* d_in, const int* in_sizes, int n_in,
                              void* d_out, int out_size, void* d_ws, size_t ws_size,
                              hipStream_t stream)
{
  const float* x    = (const float*)d_in[0];
  const float* g_w  = (const float*)d_in[1];
  const float* th_w = (const float*)d_in[3];
  const float* ph_w = (const float*)d_in[5];
  const float* W_w  = (const float*)d_in[7];

  char* ws = (char*)d_ws;
  const size_t MB = 1024ull * 1024ull;
  if (ws_size < 186 * MB) return;  // need ~186MB of scratch

  // region map (reused over time):
  // [0,32)MB    xT_hi  -> later znorm_hi
  // [32,64)MB   xT_lo  -> later znorm_lo
  // [64,160)MB  z_all  -> later fpart(64..72) / attn(72..) / y4T(80..96)
  // [160,176)MB gT
  // [176,177)MB weights + stats
  unsigned short* xT_hi    = (unsigned short*)(ws);
  unsigned short* xT_lo    = (unsigned short*)(ws + 32 * MB);
  float*          z_all    = (float*)(ws + 64 * MB);
  unsigned short* znorm_hi = (unsigned short*)(ws);            // reuse xT_hi
  unsigned short* znorm_lo = (unsigned short*)(ws + 32 * MB);  // reuse xT_lo
  float*          fpart    = (float*)(ws + 64 * MB);           // reuse z_all
  unsigned short* attn     = (unsigned short*)(ws + 72 * MB);
  unsigned short* y4T      = (unsigned short*)(ws + 80 * MB);
  unsigned short* gT       = (unsigned short*)(ws + 160 * MB);
  unsigned short* whi      = (unsigned short*)(ws + 176 * MB);
  unsigned short* wlo      = (unsigned short*)(ws + 176 * MB + 256 * 1024);
  unsigned short* wgh      = (unsigned short*)(ws + 176 * MB + 512 * 1024);
  unsigned short* w2h      = (unsigned short*)(ws + 176 * MB + 640 * 1024);
  float*          statsg   = (float*)(ws + 176 * MB + 768 * 1024);

  // 1) weight prep, x transpose+split
  prep_weights<<<dim3(256), 256, 0, stream>>>(g_w, th_w, ph_w, W_w, whi, wlo, wgh, w2h);
  transpose_split_x<<<dim3(64, 4, 16), 256, 0, stream>>>(x, xT_hi, xT_lo);

  // 2) theta/phi projection (split 3-pass): z_all[b][0..255][4096]
  gemm_tn<3, false><<<dim3(32, 2, 16), 256, 0, stream>>>(
      whi, wlo, xT_hi, xT_lo, z_all,
      256, 256, 4096, 4, 1,
      0, 0, 0, (long)4096 * 256, 0, (long)384 * 4096);

  // 3) g projection (bf16 1-pass): z_all[b][256..383][4096]
  gemm_tn<1, false><<<dim3(32, 1, 16), 256, 0, stream>>>(
      wgh, nullptr, xT_hi, nullptr, z_all + (long)256 * 4096,
      256, 256, 4096, 4, 1,
      0, 0, 0, (long)4096 * 256, 0, (long)384 * 4096);

  // 4) normalize+relu+split theta/phi (overwrites xT region)
  norm_split<<<dim3(4096), 256, 0, stream>>>(z_all, znorm_hi, znorm_lo);

  // 5) g stats, then normalize+relu+transpose g -> gT[b][n][128]
  stats_g<<<dim3(2048), 256, 0, stream>>>(z_all, statsg);
  norm_transpose_g<<<dim3(64, 16), 256, 0, stream>>>(z_all, statsg, gT);

  // 6) f = theta . phi^T, split 3-pass, K=4096 in 8 chunks (deterministic partials)
  gemm_tn<3, false><<<dim3(1, 1, 128), 256, 0, stream>>>(
      znorm_hi, znorm_lo, znorm_hi + (long)128 * 4096, znorm_lo + (long)128 * 4096, fpart,
      4096, 4096, 128, 8, 8,
      512, (long)256 * 4096, 512, (long)256 * 4096, 16384, 131072);

  // 7) softmax rows -> attn bf16
  softmax_attn<<<dim3(2048), 64, 0, stream>>>(fpart, attn);

  // 8) y = attn . g, written directly as scrambled-transposed y4T[b][p][c]
  //    per (b,r): C[i,t] = sum_j attn[i,j]*gT[r+32t][j]
  gemm_tn<1, true><<<dim3(1, 1, 512), 256, 0, stream>>>(
      attn, nullptr, gT, nullptr, y4T,
      128, 4096, 128, 2, 32,
      0, 16384, 128, (long)4096 * 128, 16384, (long)4096 * 128);

  // 9) final conv: z2[b][o][p] = sum_c W2[o,c]*y4T[b][p][c]  (fp32 into d_out)
  gemm_tn<1, false><<<dim3(32, 2, 16), 256, 0, stream>>>(
      w2h, nullptr, y4T, nullptr, d_out,
      128, 128, 4096, 2, 1,
      0, 0, 0, (long)4096 * 128, 0, (long)256 * 4096);

  // 10) instance-norm of z2 + residual x, in place in d_out
  finalize<<<dim3(4096), 256, 0, stream>>>((float*)d_out, x);
}

// Round 2
// 195.321 us; speedup vs baseline: 1.0317x; 1.0317x over previous
//
#include <hip/hip_runtime.h>

#define DEVINL __device__ __forceinline__

typedef __attribute__((ext_vector_type(8))) short bf8v;           // 8 bf16 bit-patterns (MFMA operand)
typedef __attribute__((ext_vector_type(4))) float f32x4;
typedef __attribute__((ext_vector_type(8))) unsigned short us8;
typedef __attribute__((ext_vector_type(4))) unsigned short us4;

DEVINL unsigned short f2bf(float f) {                 // round-to-nearest-even fp32->bf16
  unsigned int u = __builtin_bit_cast(unsigned int, f);
  u += 0x7fffu + ((u >> 16) & 1u);
  return (unsigned short)(u >> 16);
}
DEVINL unsigned short f2bf_trunc(float f) {           // truncate (for lo residuals)
  return (unsigned short)(__builtin_bit_cast(unsigned int, f) >> 16);
}
DEVINL float bf2f(unsigned short h) {
  unsigned int u = ((unsigned int)h) << 16;
  return __builtin_bit_cast(float, u);
}

// ------------------------------------------------------------------
// Generic TN GEMM: C[m,n] = sum_k A[m,k]*B[n,k].  A,B bf16 (optionally
// split hi/lo: 3 passes hh+hl+lh).  Tile 128x128, BK=64, 256 thr = 4
// waves 2x2, each wave 4x4 frags of 16x16x32 MFMA.
// Operand-SWAPPED mfma (b,a): lane holds 4 consecutive n -> f32x4 C-stores.
// B_FROM_X: B staged directly from fp32 x[c][n] (transpose+split in regs);
//           blockIdx.y<2 -> 3-pass rows (theta/phi), y==2 -> 1-pass (g).
// LDS rows padded to 72 shorts (144B, 16B-aligned rows).
// ------------------------------------------------------------------
template<int PASSES, bool OUT_BF16, bool B_FROM_X>
__global__ __launch_bounds__(256, 2)
void gemm_tn(const unsigned short* __restrict__ Ahi, const unsigned short* __restrict__ Alo,
             const void* __restrict__ Bsrc, const unsigned short* __restrict__ Blo,
             void* __restrict__ Cout,
             int lda, int ldb, int ldc, int ksteps, int z1count,
             long aS1, long aS2, long bS1, long bS2, long cS1, long cS2)
{
  __shared__ __align__(16) unsigned short smem[(PASSES == 3 ? 4 : 2) * 128 * 72];
  unsigned short* As_hi = smem;
  unsigned short* Bs_hi = smem + 128 * 72;
  unsigned short* As_lo = smem + 2 * 128 * 72;  // only if PASSES==3
  unsigned short* Bs_lo = smem + 3 * 128 * 72;

  const int t = threadIdx.x;
  const int lane = t & 63;
  const int wave = t >> 6;
  const int wm = wave >> 1, wn = wave & 1;
  const int lr = lane & 15, lk = lane >> 4;

  const bool three = (PASSES == 3) && (!B_FROM_X || (blockIdx.y < 2));

  const int z = blockIdx.z;
  const int zb = z / z1count, z1 = z - zb * z1count;
  const unsigned short* Ah = Ahi + zb * aS2 + z1 * aS1;
  const unsigned short* Al = (PASSES == 3) ? (Alo + zb * aS2 + z1 * aS1) : nullptr;
  const long cOff = zb * cS2 + z1 * cS1;

  const int mbase = blockIdx.y * 128;
  const int nbase = blockIdx.x * 128;

  f32x4 acc[4][4];
#pragma unroll
  for (int i = 0; i < 4; ++i)
#pragma unroll
    for (int j = 0; j < 4; ++j) acc[i][j] = (f32x4)0.0f;

  for (int kt = 0; kt < ksteps; ++kt) {
    const int k0 = kt * 64;
    if (!B_FROM_X) {
      const unsigned short* Bh = (const unsigned short*)Bsrc + zb * bS2 + z1 * bS1;
      const unsigned short* Bl = (PASSES == 3) ? (Blo + zb * bS2 + z1 * bS1) : nullptr;
#pragma unroll
      for (int i = 0; i < 4; ++i) {
        const int q = i * 256 + t;
        const int row = q >> 3, c = q & 7;
        const int lo = row * 72 + c * 8;
        *(us8*)&As_hi[lo] = *(const us8*)&Ah[(long)(mbase + row) * lda + k0 + c * 8];
        *(us8*)&Bs_hi[lo] = *(const us8*)&Bh[(long)(nbase + row) * ldb + k0 + c * 8];
        if (PASSES == 3) {
          *(us8*)&As_lo[lo] = *(const us8*)&Al[(long)(mbase + row) * lda + k0 + c * 8];
          *(us8*)&Bs_lo[lo] = *(const us8*)&Bl[(long)(nbase + row) * ldb + k0 + c * 8];
        }
      }
    } else {
      // A-tile (weights) staging
#pragma unroll
      for (int i = 0; i < 4; ++i) {
        const int q = i * 256 + t;
        const int row = q >> 3, c = q & 7;
        const int lo = row * 72 + c * 8;
        *(us8*)&As_hi[lo] = *(const us8*)&Ah[(long)(mbase + row) * lda + k0 + c * 8];
        if (three) *(us8*)&As_lo[lo] = *(const us8*)&Al[(long)(mbase + row) * lda + k0 + c * 8];
      }
      // B-tile from fp32 x[c][n]: lane-per-n, 32 c's per thread; split hi/lo
      const float* xs = (const float*)Bsrc + zb * bS2;
      const int nl = t & 127, cg = t >> 7;
      float xv[32];
#pragma unroll
      for (int i = 0; i < 32; ++i)
        xv[i] = xs[(long)(k0 + cg * 32 + i) * ldb + nbase + nl];
#pragma unroll
      for (int ch = 0; ch < 4; ++ch) {
        us8 h8, l8;
#pragma unroll
        for (int e = 0; e < 8; ++e) {
          const float v = xv[ch * 8 + e];
          const unsigned short hb = f2bf(v);
          h8[e] = hb;
          l8[e] = f2bf_trunc(v - bf2f(hb));
        }
        *(us8*)&Bs_hi[nl * 72 + cg * 32 + ch * 8] = h8;
        if (three) *(us8*)&Bs_lo[nl * 72 + cg * 32 + ch * 8] = l8;
      }
    }
    __syncthreads();
#pragma unroll
    for (int ks = 0; ks < 2; ++ks) {
      const int ko = ks * 32 + lk * 8;
      bf8v ah[4], bh[4], al[4], bl[4];
#pragma unroll
      for (int mi = 0; mi < 4; ++mi) {
        const int r = (wm * 64 + mi * 16 + lr) * 72 + ko;
        ah[mi] = *(const bf8v*)&As_hi[r];
        if (three) al[mi] = *(const bf8v*)&As_lo[r];
      }
#pragma unroll
      for (int ni = 0; ni < 4; ++ni) {
        const int r = (wn * 64 + ni * 16 + lr) * 72 + ko;
        bh[ni] = *(const bf8v*)&Bs_hi[r];
        if (three) bl[ni] = *(const bf8v*)&Bs_lo[r];
      }
      // swapped operands: D row <-> B rows (n), D col <-> A rows (m)
#pragma unroll
      for (int mi = 0; mi < 4; ++mi)
#pragma unroll
        for (int ni = 0; ni < 4; ++ni) {
          acc[mi][ni] = __builtin_amdgcn_mfma_f32_16x16x32_bf16(bh[ni], ah[mi], acc[mi][ni], 0, 0, 0);
          if (three) {
            acc[mi][ni] = __builtin_amdgcn_mfma_f32_16x16x32_bf16(bl[ni], ah[mi], acc[mi][ni], 0, 0, 0);
            acc[mi][ni] = __builtin_amdgcn_mfma_f32_16x16x32_bf16(bh[ni], al[mi], acc[mi][ni], 0, 0, 0);
          }
        }
    }
    __syncthreads();
  }

  // epilogue (swapped layout): lane&15 -> m, (lane>>4)*4+r -> n => vector stores
#pragma unroll
  for (int mi = 0; mi < 4; ++mi)
#pragma unroll
    for (int ni = 0; ni < 4; ++ni) {
      const int gm = mbase + wm * 64 + mi * 16 + lr;
      const int gn = nbase + wn * 64 + ni * 16 + lk * 4;
      const f32x4 v = acc[mi][ni];
      if (OUT_BF16) {
        us4 o;
#pragma unroll
        for (int r = 0; r < 4; ++r) o[r] = f2bf(v[r]);
        *(us4*)&((unsigned short*)Cout)[cOff + (long)gm * ldc + gn] = o;
      } else {
        *(f32x4*)&((float*)Cout)[cOff + (long)gm * ldc + gn] = v;
      }
    }
}

// ------------------------------------------------------------------
// weights: wall rows [0..127]=theta, [128..255]=phi (hi+lo), [256..383]=g (hi);
// W2 -> bf16 [256][128]
// ------------------------------------------------------------------
__global__ __launch_bounds__(256)
void prep_weights(const float* __restrict__ g_w, const float* __restrict__ th_w,
                  const float* __restrict__ ph_w, const float* __restrict__ W_w,
                  unsigned short* __restrict__ wall_hi, unsigned short* __restrict__ wall_lo,
                  unsigned short* __restrict__ w2h)
{
  const int i = blockIdx.x * 256 + threadIdx.x;  // [0, 98304)
  float v;
  if (i < 32768) v = th_w[i];
  else if (i < 65536) v = ph_w[i - 32768];
  else v = g_w[i - 65536];
  const unsigned short h = f2bf(v);
  wall_hi[i] = h;
  if (i < 65536) wall_lo[i] = f2bf_trunc(v - bf2f(h));
  if (i < 32768) w2h[i] = f2bf(W_w[i]);
}

// ------------------------------------------------------------------
// per-row instance-norm + relu + hi/lo split for theta/phi rows
// z_all [b][384][4096]; rows 0..255 -> znorm hi/lo [b][256][4096]
// ------------------------------------------------------------------
__global__ __launch_bounds__(256)
void norm_split(const float* __restrict__ z,
                unsigned short* __restrict__ nhi, unsigned short* __restrict__ nlo)
{
  const int row = blockIdx.x;            // b*256 + m
  const int b = row >> 8, m = row & 255;
  const float* src = z + ((long)b * 384 + m) * 4096;
  const int t = threadIdx.x;
  f32x4 v[4];
  float s = 0.f, ss = 0.f;
#pragma unroll
  for (int i = 0; i < 4; ++i) {
    v[i] = *(const f32x4*)&src[i * 1024 + t * 4];
#pragma unroll
    for (int e = 0; e < 4; ++e) { s += v[i][e]; ss += v[i][e] * v[i][e]; }
  }
  __shared__ float r0[256], r1[256];
  r0[t] = s; r1[t] = ss;
  __syncthreads();
  for (int o = 128; o > 0; o >>= 1) {
    if (t < o) { r0[t] += r0[t + o]; r1[t] += r1[t + o]; }
    __syncthreads();
  }
  const float mean = r0[0] * (1.f / 4096.f);
  const float var = r1[0] * (1.f / 4096.f) - mean * mean;
  const float rs = rsqrtf(fmaxf(var, 0.f) + 1e-5f);
  const long obase = (long)row * 4096;
#pragma unroll
  for (int i = 0; i < 4; ++i) {
    us4 hi, lo;
#pragma unroll
    for (int e = 0; e < 4; ++e) {
      const float nv = fmaxf((v[i][e] - mean) * rs, 0.f);
      const unsigned short h = f2bf(nv);
      hi[e] = h;
      lo[e] = f2bf_trunc(nv - bf2f(h));
    }
    *(us4*)&nhi[obase + i * 1024 + t * 4] = hi;
    *(us4*)&nlo[obase + i * 1024 + t * 4] = lo;
  }
}

// ------------------------------------------------------------------
// stats for g rows (z_all rows 256..383): mean + rsig per (b,j)
// ------------------------------------------------------------------
__global__ __launch_bounds__(256)
void stats_g(const float* __restrict__ z, float* __restrict__ statsg)
{
  const int row = blockIdx.x;            // b*128 + j
  const int b = row >> 7, j = row & 127;
  const float* src = z + ((long)b * 384 + 256 + j) * 4096;
  const int t = threadIdx.x;
  float s = 0.f, ss = 0.f;
#pragma unroll
  for (int i = 0; i < 4; ++i) {
    f32x4 v = *(const f32x4*)&src[i * 1024 + t * 4];
#pragma unroll
    for (int e = 0; e < 4; ++e) { s += v[e]; ss += v[e] * v[e]; }
  }
  __shared__ float r0[256], r1[256];
  r0[t] = s; r1[t] = ss;
  __syncthreads();
  for (int o = 128; o > 0; o >>= 1) {
    if (t < o) { r0[t] += r0[t + o]; r1[t] += r1[t + o]; }
    __syncthreads();
  }
  if (t == 0) {
    const float mean = r0[0] * (1.f / 4096.f);
    const float var = r1[0] * (1.f / 4096.f) - mean * mean;
    statsg[row * 2] = mean;
    statsg[row * 2 + 1] = rsqrtf(fmaxf(var, 0.f) + 1e-5f);
  }
}

// ------------------------------------------------------------------
// normalize + relu + transpose g: z rows 256..383 -> gT [b][n][128] bf16
// ------------------------------------------------------------------
__global__ __launch_bounds__(256)
void norm_transpose_g(const float* __restrict__ z, const float* __restrict__ statsg,
                      unsigned short* __restrict__ gT)
{
  __shared__ unsigned short T[64 * 136];
  const int b = blockIdx.y, n0 = blockIdx.x * 64;
  const int t = threadIdx.x;
  const int c = t >> 1, part = t & 1;
  const float mu = statsg[(b * 128 + c) * 2];
  const float rs = statsg[(b * 128 + c) * 2 + 1];
  const float* src = z + ((long)b * 384 + 256 + c) * 4096 + n0 + part * 32;
#pragma unroll
  for (int j = 0; j < 8; ++j) {
    f32x4 v = *(const f32x4*)&src[j * 4];
#pragma unroll
    for (int e = 0; e < 4; ++e) {
      const float nv = fmaxf((v[e] - mu) * rs, 0.f);
      T[(part * 32 + j * 4 + e) * 136 + c] = f2bf(nv);
    }
  }
  __syncthreads();
  const int nl = t >> 2, q = t & 3;
  const long obase = ((long)b * 4096 + n0 + nl) * 128 + q * 32;
#pragma unroll
  for (int k = 0; k < 4; ++k) {
    us8 o;
#pragma unroll
    for (int e = 0; e < 8; ++e) o[e] = T[nl * 136 + q * 32 + k * 8 + e];
    *(us8*)&gT[obase + k * 8] = o;
  }
}

// ------------------------------------------------------------------
// softmax over j: sums 16 deterministic K-split partials, writes attn bf16
// ------------------------------------------------------------------
__global__ __launch_bounds__(64)
void softmax_attn(const float* __restrict__ fpart, unsigned short* __restrict__ attn)
{
  const int row = blockIdx.x;            // b*128 + i
  const int b = row >> 7, i = row & 127;
  const int t = threadIdx.x;
  float v0 = 0.f, v1 = 0.f;
#pragma unroll
  for (int kc = 0; kc < 16; ++kc) {
    const float* p = fpart + ((long)(b * 16 + kc)) * 16384 + i * 128;
    v0 += p[t];
    v1 += p[t + 64];
  }
  float mx = fmaxf(v0, v1);
  for (int o = 32; o > 0; o >>= 1) mx = fmaxf(mx, __shfl_xor(mx, o));
  const float e0 = __expf(v0 - mx), e1 = __expf(v1 - mx);
  float s = e0 + e1;
  for (int o = 32; o > 0; o >>= 1) s += __shfl_xor(s, o);
  const float inv = 1.f / s;
  attn[(long)row * 128 + t] = f2bf(e0 * inv);
  attn[(long)row * 128 + t + 64] = f2bf(e1 * inv);
}

// ------------------------------------------------------------------
// final: per-row instance-norm of z2 (in d_out) + residual x, in place
// ------------------------------------------------------------------
__global__ __launch_bounds__(256)
void finalize(float* __restrict__ out, const float* __restrict__ x)
{
  const int row = blockIdx.x;            // b*256 + o
  const long base = (long)row * 4096;
  const int t = threadIdx.x;
  f32x4 v[4];
  float s = 0.f, ss = 0.f;
#pragma unroll
  for (int i = 0; i < 4; ++i) {
    v[i] = *(const f32x4*)&out[base + i * 1024 + t * 4];
#pragma unroll
    for (int e = 0; e < 4; ++e) { s += v[i][e]; ss += v[i][e] * v[i][e]; }
  }
  __shared__ float r0[256], r1[256];
  r0[t] = s; r1[t] = ss;
  __syncthreads();
  for (int o = 128; o > 0; o >>= 1) {
    if (t < o) { r0[t] += r0[t + o]; r1[t] += r1[t + o]; }
    __syncthreads();
  }
  const float mean = r0[0] * (1.f / 4096.f);
  const float var = r1[0] * (1.f / 4096.f) - mean * mean;
  const float rs = rsqrtf(fmaxf(var, 0.f) + 1e-5f);
#pragma unroll
  for (int i = 0; i < 4; ++i) {
    f32x4 xr = *(const f32x4*)&x[base + i * 1024 + t * 4];
    f32x4 o;
#pragma unroll
    for (int e = 0; e < 4; ++e) o[e] = (v[i][e] - mean) * rs + xr[e];
    *(f32x4*)&out[base + i * 1024 + t * 4] = o;
  }
}

// ------------------------------------------------------------------
extern "C" void kernel_launch(void* const* d_in, const int* in_sizes, int n_in,
                              void* d_out, int out_size, void* d_ws, size_t ws_size,
                              hipStream_t stream)
{
  const float* x    = (const float*)d_in[0];
  const float* g_w  = (const float*)d_in[1];
  const float* th_w = (const float*)d_in[3];
  const float* ph_w = (const float*)d_in[5];
  const float* W_w  = (const float*)d_in[7];

  char* ws = (char*)d_ws;
  const size_t MB = 1024ull * 1024ull;
  if (ws_size < 186 * MB) return;

  // region map (time-multiplexed):
  // [0,64)    znorm hi/lo (written by norm_split, read by f-GEMM)
  // [64,160)  z_all (proj out) -> later fpart[64,80) / attn[80,81) / y4T[82,99)
  // [160,176) gT
  // [176,..)  weights + stats
  unsigned short* znorm_hi = (unsigned short*)(ws);
  unsigned short* znorm_lo = (unsigned short*)(ws + 32 * MB);
  float*          z_all    = (float*)(ws + 64 * MB);
  float*          fpart    = (float*)(ws + 64 * MB);
  unsigned short* attn     = (unsigned short*)(ws + 80 * MB);
  unsigned short* y4T      = (unsigned short*)(ws + 82 * MB);
  unsigned short* gT       = (unsigned short*)(ws + 160 * MB);
  unsigned short* wall_hi  = (unsigned short*)(ws + 176 * MB);
  unsigned short* wall_lo  = (unsigned short*)(ws + 176 * MB + 256 * 1024);
  unsigned short* w2h      = (unsigned short*)(ws + 176 * MB + 512 * 1024);
  float*          statsg   = (float*)(ws + 176 * MB + 640 * 1024);

  // 1) weight prep
  prep_weights<<<dim3(384), 256, 0, stream>>>(g_w, th_w, ph_w, W_w, wall_hi, wall_lo, w2h);

  // 2) fused projection: theta/phi (3-pass, y=0,1) + g (1-pass, y=2),
  //    B staged straight from fp32 x (transpose+split in-kernel)
  gemm_tn<3, false, true><<<dim3(32, 3, 16), 256, 0, stream>>>(
      wall_hi, wall_lo, x, nullptr, z_all,
      256, 4096, 4096, 4, 1,
      0, 0, 0, (long)256 * 4096, 0, (long)384 * 4096);

  // 3) normalize+relu+split theta/phi -> znorm hi/lo
  norm_split<<<dim3(4096), 256, 0, stream>>>(z_all, znorm_hi, znorm_lo);

  // 4) g stats, then normalize+relu+transpose g -> gT[b][n][128]
  stats_g<<<dim3(2048), 256, 0, stream>>>(z_all, statsg);
  norm_transpose_g<<<dim3(64, 16), 256, 0, stream>>>(z_all, statsg, gT);

  // 5) f = theta . phi^T, split 3-pass, K=4096 in 16 chunks (256 blocks)
  gemm_tn<3, false, false><<<dim3(1, 1, 256), 256, 0, stream>>>(
      znorm_hi, znorm_lo, znorm_hi + (long)128 * 4096, znorm_lo + (long)128 * 4096, fpart,
      4096, 4096, 128, 4, 16,
      256, (long)256 * 4096, 256, (long)256 * 4096, 16384, 262144);

  // 6) softmax rows -> attn bf16
  softmax_attn<<<dim3(2048), 64, 0, stream>>>(fpart, attn);

  // 7) y = attn . g, written directly as scrambled-transposed y4T[b][p][c]
  gemm_tn<1, true, false><<<dim3(1, 1, 512), 256, 0, stream>>>(
      attn, nullptr, gT, nullptr, y4T,
      128, 4096, 128, 2, 32,
      0, 16384, 128, (long)4096 * 128, 16384, (long)4096 * 128);

  // 8) final conv: z2[b][o][p] = sum_c W2[o,c]*y4T[b][p][c]  (fp32 into d_out)
  gemm_tn<1, false, false><<<dim3(32, 2, 16), 256, 0, stream>>>(
      w2h, nullptr, y4T, nullptr, d_out,
      128, 128, 4096, 2, 1,
      0, 0, 0, (long)4096 * 128, 0, (long)256 * 4096);

  // 9) instance-norm of z2 + residual x, in place in d_out
  finalize<<<dim3(4096), 256, 0, stream>>>((float*)d_out, x);
}

// Round 3
// 181.062 us; speedup vs baseline: 1.1130x; 1.0788x over previous
//
#include <hip/hip_runtime.h>

#define DEVINL __device__ __forceinline__

typedef __attribute__((ext_vector_type(8))) short bf8v;           // 8 bf16 bit-patterns (MFMA operand)
typedef __attribute__((ext_vector_type(4))) float f32x4;
typedef __attribute__((ext_vector_type(8))) unsigned short us8;
typedef __attribute__((ext_vector_type(4))) unsigned short us4;

DEVINL unsigned short f2bf(float f) {                 // round-to-nearest-even fp32->bf16
  unsigned int u = __builtin_bit_cast(unsigned int, f);
  u += 0x7fffu + ((u >> 16) & 1u);
  return (unsigned short)(u >> 16);
}
DEVINL unsigned short f2bf_trunc(float f) {           // truncate (for lo residuals)
  return (unsigned short)(__builtin_bit_cast(unsigned int, f) >> 16);
}
DEVINL float bf2f(unsigned short h) {
  unsigned int u = ((unsigned int)h) << 16;
  return __builtin_bit_cast(float, u);
}

// ------------------------------------------------------------------
// Fused projection: z[b][m][n] for m in [0,384) = theta(0..127),
// phi(128..255) [3-pass split] and g(256..383) [1-pass].
// One block = full M=384 x 128-n tile; B staged once from fp32 x
// (transpose + hi/lo split in registers). 512 thr = 8 waves (4m x 2n);
// frag rows interleaved (fr = mi*4+wm) so every wave gets 4 split-pass
// frags + 2 single-pass frags (balanced MFMA load).
// ------------------------------------------------------------------
__global__ __launch_bounds__(512, 2)
void proj_gemm(const unsigned short* __restrict__ wall_hi,
               const unsigned short* __restrict__ wall_lo,
               const float* __restrict__ x, float* __restrict__ z)
{
  __shared__ __align__(16) unsigned short As_hi[384 * 72];
  __shared__ __align__(16) unsigned short As_lo[256 * 72];
  __shared__ __align__(16) unsigned short Bs_hi[128 * 72];
  __shared__ __align__(16) unsigned short Bs_lo[128 * 72];

  const int t = threadIdx.x;
  const int lane = t & 63;
  const int wave = t >> 6;                 // 0..7
  const int wm = wave >> 1, wn = wave & 1; // 4 x 2
  const int lr = lane & 15, lk = lane >> 4;
  const int b = blockIdx.z;
  const int nbase = blockIdx.x * 128;
  const float* xs = x + (long)b * 256 * 4096;

  f32x4 acc[6][4];
#pragma unroll
  for (int i = 0; i < 6; ++i)
#pragma unroll
    for (int j = 0; j < 4; ++j) acc[i][j] = (f32x4)0.0f;

  for (int kt = 0; kt < 4; ++kt) {
    const int k0 = kt * 64;
    // A hi: 384 rows x 8 us8-chunks = 3072 -> 6 per thread
#pragma unroll
    for (int i = 0; i < 6; ++i) {
      const int q = i * 512 + t;
      const int row = q >> 3, c = q & 7;
      *(us8*)&As_hi[row * 72 + c * 8] = *(const us8*)&wall_hi[(long)row * 256 + k0 + c * 8];
    }
    // A lo: 256 rows x 8 = 2048 -> 4 per thread
#pragma unroll
    for (int i = 0; i < 4; ++i) {
      const int q = i * 512 + t;
      const int row = q >> 3, c = q & 7;
      *(us8*)&As_lo[row * 72 + c * 8] = *(const us8*)&wall_lo[(long)row * 256 + k0 + c * 8];
    }
    // B from fp32 x[c][n]: 64 c x 128 n; lane-major n -> coalesced
    const int nl = t & 127, cg = t >> 7;   // cg 0..3, 16 c each
    float xv[16];
#pragma unroll
    for (int i = 0; i < 16; ++i)
      xv[i] = xs[(long)(k0 + cg * 16 + i) * 4096 + nbase + nl];
#pragma unroll
    for (int ch = 0; ch < 2; ++ch) {
      us8 h8, l8;
#pragma unroll
      for (int e = 0; e < 8; ++e) {
        const float v = xv[ch * 8 + e];
        const unsigned short hb = f2bf(v);
        h8[e] = hb;
        l8[e] = f2bf_trunc(v - bf2f(hb));
      }
      *(us8*)&Bs_hi[nl * 72 + cg * 16 + ch * 8] = h8;
      *(us8*)&Bs_lo[nl * 72 + cg * 16 + ch * 8] = l8;
    }
    __syncthreads();
#pragma unroll
    for (int ks = 0; ks < 2; ++ks) {
      const int ko = ks * 32 + lk * 8;
      bf8v bh[4], bl[4];
#pragma unroll
      for (int ni = 0; ni < 4; ++ni) {
        const int r = (wn * 64 + ni * 16 + lr) * 72 + ko;
        bh[ni] = *(const bf8v*)&Bs_hi[r];
        bl[ni] = *(const bf8v*)&Bs_lo[r];
      }
#pragma unroll
      for (int mi = 0; mi < 6; ++mi) {
        const int fr = mi * 4 + wm;        // frag row 0..23 (row16 block)
        const int r = (fr * 16 + lr) * 72 + ko;
        const bf8v ah = *(const bf8v*)&As_hi[r];
        if (fr < 16) {                      // theta/phi rows: 3-pass split
          const bf8v al = *(const bf8v*)&As_lo[r];
#pragma unroll
          for (int ni = 0; ni < 4; ++ni) {
            acc[mi][ni] = __builtin_amdgcn_mfma_f32_16x16x32_bf16(bh[ni], ah, acc[mi][ni], 0, 0, 0);
            acc[mi][ni] = __builtin_amdgcn_mfma_f32_16x16x32_bf16(bl[ni], ah, acc[mi][ni], 0, 0, 0);
            acc[mi][ni] = __builtin_amdgcn_mfma_f32_16x16x32_bf16(bh[ni], al, acc[mi][ni], 0, 0, 0);
          }
        } else {                            // g rows: 1-pass
#pragma unroll
          for (int ni = 0; ni < 4; ++ni)
            acc[mi][ni] = __builtin_amdgcn_mfma_f32_16x16x32_bf16(bh[ni], ah, acc[mi][ni], 0, 0, 0);
        }
      }
    }
    __syncthreads();
  }
  // epilogue (swapped layout): col(lr) -> m, row(lk*4+r) -> n
#pragma unroll
  for (int mi = 0; mi < 6; ++mi)
#pragma unroll
    for (int ni = 0; ni < 4; ++ni) {
      const int gm = (mi * 4 + wm) * 16 + lr;
      const int gn = nbase + wn * 64 + ni * 16 + lk * 4;
      *(f32x4*)&z[((long)b * 384 + gm) * 4096 + gn] = acc[mi][ni];
    }
}

// ------------------------------------------------------------------
// Generic TN GEMM (f / y / conv2): C[m,n] = sum_k A[m,k]*B[n,k].
// Swapped-operand mfma -> vector C-stores. Tile 128x128, BK=64,
// 256 thr = 4 waves 2x2. LDS rows padded to 72 shorts.
// ------------------------------------------------------------------
template<int PASSES, bool OUT_BF16>
__global__ __launch_bounds__(256, 2)
void gemm_tn(const unsigned short* __restrict__ Ahi, const unsigned short* __restrict__ Alo,
             const unsigned short* __restrict__ Bhi, const unsigned short* __restrict__ Blo,
             void* __restrict__ Cout,
             int lda, int ldb, int ldc, int ksteps, int z1count,
             long aS1, long aS2, long bS1, long bS2, long cS1, long cS2)
{
  __shared__ __align__(16) unsigned short smem[(PASSES == 3 ? 4 : 2) * 128 * 72];
  unsigned short* As_hi = smem;
  unsigned short* Bs_hi = smem + 128 * 72;
  unsigned short* As_lo = smem + 2 * 128 * 72;
  unsigned short* Bs_lo = smem + 3 * 128 * 72;

  const int t = threadIdx.x;
  const int lane = t & 63;
  const int wave = t >> 6;
  const int wm = wave >> 1, wn = wave & 1;
  const int lr = lane & 15, lk = lane >> 4;

  const int z = blockIdx.z;
  const int zb = z / z1count, z1 = z - zb * z1count;
  const unsigned short* Ah = Ahi + zb * aS2 + z1 * aS1;
  const unsigned short* Bh = Bhi + zb * bS2 + z1 * bS1;
  const unsigned short* Al = (PASSES == 3) ? (Alo + zb * aS2 + z1 * aS1) : nullptr;
  const unsigned short* Bl = (PASSES == 3) ? (Blo + zb * bS2 + z1 * bS1) : nullptr;
  const long cOff = zb * cS2 + z1 * cS1;

  const int mbase = blockIdx.y * 128;
  const int nbase = blockIdx.x * 128;

  f32x4 acc[4][4];
#pragma unroll
  for (int i = 0; i < 4; ++i)
#pragma unroll
    for (int j = 0; j < 4; ++j) acc[i][j] = (f32x4)0.0f;

  for (int kt = 0; kt < ksteps; ++kt) {
    const int k0 = kt * 64;
#pragma unroll
    for (int i = 0; i < 4; ++i) {
      const int q = i * 256 + t;
      const int row = q >> 3, c = q & 7;
      const int lo = row * 72 + c * 8;
      *(us8*)&As_hi[lo] = *(const us8*)&Ah[(long)(mbase + row) * lda + k0 + c * 8];
      *(us8*)&Bs_hi[lo] = *(const us8*)&Bh[(long)(nbase + row) * ldb + k0 + c * 8];
      if (PASSES == 3) {
        *(us8*)&As_lo[lo] = *(const us8*)&Al[(long)(mbase + row) * lda + k0 + c * 8];
        *(us8*)&Bs_lo[lo] = *(const us8*)&Bl[(long)(nbase + row) * ldb + k0 + c * 8];
      }
    }
    __syncthreads();
#pragma unroll
    for (int ks = 0; ks < 2; ++ks) {
      const int ko = ks * 32 + lk * 8;
      bf8v ah[4], bh[4], al[4], bl[4];
#pragma unroll
      for (int mi = 0; mi < 4; ++mi) {
        const int r = (wm * 64 + mi * 16 + lr) * 72 + ko;
        ah[mi] = *(const bf8v*)&As_hi[r];
        if (PASSES == 3) al[mi] = *(const bf8v*)&As_lo[r];
      }
#pragma unroll
      for (int ni = 0; ni < 4; ++ni) {
        const int r = (wn * 64 + ni * 16 + lr) * 72 + ko;
        bh[ni] = *(const bf8v*)&Bs_hi[r];
        if (PASSES == 3) bl[ni] = *(const bf8v*)&Bs_lo[r];
      }
#pragma unroll
      for (int mi = 0; mi < 4; ++mi)
#pragma unroll
        for (int ni = 0; ni < 4; ++ni) {
          acc[mi][ni] = __builtin_amdgcn_mfma_f32_16x16x32_bf16(bh[ni], ah[mi], acc[mi][ni], 0, 0, 0);
          if (PASSES == 3) {
            acc[mi][ni] = __builtin_amdgcn_mfma_f32_16x16x32_bf16(bl[ni], ah[mi], acc[mi][ni], 0, 0, 0);
            acc[mi][ni] = __builtin_amdgcn_mfma_f32_16x16x32_bf16(bh[ni], al[mi], acc[mi][ni], 0, 0, 0);
          }
        }
    }
    __syncthreads();
  }

#pragma unroll
  for (int mi = 0; mi < 4; ++mi)
#pragma unroll
    for (int ni = 0; ni < 4; ++ni) {
      const int gm = mbase + wm * 64 + mi * 16 + lr;
      const int gn = nbase + wn * 64 + ni * 16 + lk * 4;
      const f32x4 v = acc[mi][ni];
      if (OUT_BF16) {
        us4 o;
#pragma unroll
        for (int r = 0; r < 4; ++r) o[r] = f2bf(v[r]);
        *(us4*)&((unsigned short*)Cout)[cOff + (long)gm * ldc + gn] = o;
      } else {
        *(f32x4*)&((float*)Cout)[cOff + (long)gm * ldc + gn] = v;
      }
    }
}

// ------------------------------------------------------------------
// weights: wall rows [0..127]=theta, [128..255]=phi (hi+lo), [256..383]=g (hi);
// W2 -> bf16 [256][128]
// ------------------------------------------------------------------
__global__ __launch_bounds__(256)
void prep_weights(const float* __restrict__ g_w, const float* __restrict__ th_w,
                  const float* __restrict__ ph_w, const float* __restrict__ W_w,
                  unsigned short* __restrict__ wall_hi, unsigned short* __restrict__ wall_lo,
                  unsigned short* __restrict__ w2h)
{
  const int i = blockIdx.x * 256 + threadIdx.x;  // [0, 98304)
  float v;
  if (i < 32768) v = th_w[i];
  else if (i < 65536) v = ph_w[i - 32768];
  else v = g_w[i - 65536];
  const unsigned short h = f2bf(v);
  wall_hi[i] = h;
  if (i < 65536) wall_lo[i] = f2bf_trunc(v - bf2f(h));
  if (i < 32768) w2h[i] = f2bf(W_w[i]);
}

// ------------------------------------------------------------------
// per-row instance-norm + relu + hi/lo split for theta/phi rows
// ------------------------------------------------------------------
__global__ __launch_bounds__(256)
void norm_split(const float* __restrict__ z,
                unsigned short* __restrict__ nhi, unsigned short* __restrict__ nlo)
{
  const int row = blockIdx.x;            // b*256 + m
  const int b = row >> 8, m = row & 255;
  const float* src = z + ((long)b * 384 + m) * 4096;
  const int t = threadIdx.x;
  f32x4 v[4];
  float s = 0.f, ss = 0.f;
#pragma unroll
  for (int i = 0; i < 4; ++i) {
    v[i] = *(const f32x4*)&src[i * 1024 + t * 4];
#pragma unroll
    for (int e = 0; e < 4; ++e) { s += v[i][e]; ss += v[i][e] * v[i][e]; }
  }
  __shared__ float r0[256], r1[256];
  r0[t] = s; r1[t] = ss;
  __syncthreads();
  for (int o = 128; o > 0; o >>= 1) {
    if (t < o) { r0[t] += r0[t + o]; r1[t] += r1[t + o]; }
    __syncthreads();
  }
  const float mean = r0[0] * (1.f / 4096.f);
  const float var = r1[0] * (1.f / 4096.f) - mean * mean;
  const float rs = rsqrtf(fmaxf(var, 0.f) + 1e-5f);
  const long obase = (long)row * 4096;
#pragma unroll
  for (int i = 0; i < 4; ++i) {
    us4 hi, lo;
#pragma unroll
    for (int e = 0; e < 4; ++e) {
      const float nv = fmaxf((v[i][e] - mean) * rs, 0.f);
      const unsigned short h = f2bf(nv);
      hi[e] = h;
      lo[e] = f2bf_trunc(nv - bf2f(h));
    }
    *(us4*)&nhi[obase + i * 1024 + t * 4] = hi;
    *(us4*)&nlo[obase + i * 1024 + t * 4] = lo;
  }
}

// ------------------------------------------------------------------
// stats for g rows: mean + rsig per (b,j)
// ------------------------------------------------------------------
__global__ __launch_bounds__(256)
void stats_g(const float* __restrict__ z, float* __restrict__ statsg)
{
  const int row = blockIdx.x;            // b*128 + j
  const int b = row >> 7, j = row & 127;
  const float* src = z + ((long)b * 384 + 256 + j) * 4096;
  const int t = threadIdx.x;
  float s = 0.f, ss = 0.f;
#pragma unroll
  for (int i = 0; i < 4; ++i) {
    f32x4 v = *(const f32x4*)&src[i * 1024 + t * 4];
#pragma unroll
    for (int e = 0; e < 4; ++e) { s += v[e]; ss += v[e] * v[e]; }
  }
  __shared__ float r0[256], r1[256];
  r0[t] = s; r1[t] = ss;
  __syncthreads();
  for (int o = 128; o > 0; o >>= 1) {
    if (t < o) { r0[t] += r0[t + o]; r1[t] += r1[t + o]; }
    __syncthreads();
  }
  if (t == 0) {
    const float mean = r0[0] * (1.f / 4096.f);
    const float var = r1[0] * (1.f / 4096.f) - mean * mean;
    statsg[row * 2] = mean;
    statsg[row * 2 + 1] = rsqrtf(fmaxf(var, 0.f) + 1e-5f);
  }
}

// ------------------------------------------------------------------
// normalize + relu + transpose g: z rows 256..383 -> gT [b][n][128] bf16
// ------------------------------------------------------------------
__global__ __launch_bounds__(256)
void norm_transpose_g(const float* __restrict__ z, const float* __restrict__ statsg,
                      unsigned short* __restrict__ gT)
{
  __shared__ unsigned short T[64 * 136];
  const int b = blockIdx.y, n0 = blockIdx.x * 64;
  const int t = threadIdx.x;
  const int c = t >> 1, part = t & 1;
  const float mu = statsg[(b * 128 + c) * 2];
  const float rs = statsg[(b * 128 + c) * 2 + 1];
  const float* src = z + ((long)b * 384 + 256 + c) * 4096 + n0 + part * 32;
#pragma unroll
  for (int j = 0; j < 8; ++j) {
    f32x4 v = *(const f32x4*)&src[j * 4];
#pragma unroll
    for (int e = 0; e < 4; ++e) {
      const float nv = fmaxf((v[e] - mu) * rs, 0.f);
      T[(part * 32 + j * 4 + e) * 136 + c] = f2bf(nv);
    }
  }
  __syncthreads();
  const int nl = t >> 2, q = t & 3;
  const long obase = ((long)b * 4096 + n0 + nl) * 128 + q * 32;
#pragma unroll
  for (int k = 0; k < 4; ++k) {
    us8 o;
#pragma unroll
    for (int e = 0; e < 8; ++e) o[e] = T[nl * 136 + q * 32 + k * 8 + e];
    *(us8*)&gT[obase + k * 8] = o;
  }
}

// ------------------------------------------------------------------
// softmax over j: sums 32 deterministic K-split partials, writes attn bf16
// ------------------------------------------------------------------
__global__ __launch_bounds__(64)
void softmax_attn(const float* __restrict__ fpart, unsigned short* __restrict__ attn)
{
  const int row = blockIdx.x;            // b*128 + i
  const int b = row >> 7, i = row & 127;
  const int t = threadIdx.x;
  float v0 = 0.f, v1 = 0.f;
#pragma unroll
  for (int kc = 0; kc < 32; ++kc) {
    const float* p = fpart + ((long)(b * 32 + kc)) * 16384 + i * 128;
    v0 += p[t];
    v1 += p[t + 64];
  }
  float mx = fmaxf(v0, v1);
  for (int o = 32; o > 0; o >>= 1) mx = fmaxf(mx, __shfl_xor(mx, o));
  const float e0 = __expf(v0 - mx), e1 = __expf(v1 - mx);
  float s = e0 + e1;
  for (int o = 32; o > 0; o >>= 1) s += __shfl_xor(s, o);
  const float inv = 1.f / s;
  attn[(long)row * 128 + t] = f2bf(e0 * inv);
  attn[(long)row * 128 + t + 64] = f2bf(e1 * inv);
}

// ------------------------------------------------------------------
// final: instance-norm of bf16 z2 + residual x -> fp32 d_out
// ------------------------------------------------------------------
__global__ __launch_bounds__(256)
void finalize(const unsigned short* __restrict__ z2b, const float* __restrict__ x,
              float* __restrict__ out)
{
  const int row = blockIdx.x;            // b*256 + o
  const long base = (long)row * 4096;
  const int t = threadIdx.x;
  float v[16];
  float s = 0.f, ss = 0.f;
#pragma unroll
  for (int h = 0; h < 2; ++h) {
    us8 u = *(const us8*)&z2b[base + t * 16 + h * 8];
#pragma unroll
    for (int e = 0; e < 8; ++e) {
      const float f = bf2f(u[e]);
      v[h * 8 + e] = f;
      s += f; ss += f * f;
    }
  }
  __shared__ float r0[256], r1[256];
  r0[t] = s; r1[t] = ss;
  __syncthreads();
  for (int o = 128; o > 0; o >>= 1) {
    if (t < o) { r0[t] += r0[t + o]; r1[t] += r1[t + o]; }
    __syncthreads();
  }
  const float mean = r0[0] * (1.f / 4096.f);
  const float var = r1[0] * (1.f / 4096.f) - mean * mean;
  const float rs = rsqrtf(fmaxf(var, 0.f) + 1e-5f);
#pragma unroll
  for (int i = 0; i < 4; ++i) {
    f32x4 xr = *(const f32x4*)&x[base + t * 16 + i * 4];
    f32x4 o;
#pragma unroll
    for (int e = 0; e < 4; ++e) o[e] = (v[i * 4 + e] - mean) * rs + xr[e];
    *(f32x4*)&out[base + t * 16 + i * 4] = o;
  }
}

// ------------------------------------------------------------------
extern "C" void kernel_launch(void* const* d_in, const int* in_sizes, int n_in,
                              void* d_out, int out_size, void* d_ws, size_t ws_size,
                              hipStream_t stream)
{
  const float* x    = (const float*)d_in[0];
  const float* g_w  = (const float*)d_in[1];
  const float* th_w = (const float*)d_in[3];
  const float* ph_w = (const float*)d_in[5];
  const float* W_w  = (const float*)d_in[7];

  char* ws = (char*)d_ws;
  const size_t MB = 1024ull * 1024ull;
  if (ws_size < 186 * MB) return;

  // region map (time-multiplexed):
  // [0,64)    znorm hi/lo (norm_split writes; f-GEMM reads)
  // [64,160)  z_all (proj out; norm kernels read) -> then
  //           fpart[64,96) / attn[96,97) / y4T[98,114) / z2b[114,146)
  // [160,176) gT
  // [176,..)  weights + stats
  unsigned short* znorm_hi = (unsigned short*)(ws);
  unsigned short* znorm_lo = (unsigned short*)(ws + 32 * MB);
  float*          z_all    = (float*)(ws + 64 * MB);
  float*          fpart    = (float*)(ws + 64 * MB);
  unsigned short* attn     = (unsigned short*)(ws + 96 * MB);
  unsigned short* y4T      = (unsigned short*)(ws + 98 * MB);
  unsigned short* z2b      = (unsigned short*)(ws + 114 * MB);
  unsigned short* gT       = (unsigned short*)(ws + 160 * MB);
  unsigned short* wall_hi  = (unsigned short*)(ws + 176 * MB);
  unsigned short* wall_lo  = (unsigned short*)(ws + 176 * MB + 256 * 1024);
  unsigned short* w2h      = (unsigned short*)(ws + 176 * MB + 512 * 1024);
  float*          statsg   = (float*)(ws + 176 * MB + 640 * 1024);

  // 1) weight prep
  prep_weights<<<dim3(384), 256, 0, stream>>>(g_w, th_w, ph_w, W_w, wall_hi, wall_lo, w2h);

  // 2) fused M=384 projection (theta/phi split 3-pass + g 1-pass), x read once
  proj_gemm<<<dim3(32, 1, 16), 512, 0, stream>>>(wall_hi, wall_lo, x, z_all);

  // 3) normalize+relu+split theta/phi -> znorm hi/lo
  norm_split<<<dim3(4096), 256, 0, stream>>>(z_all, znorm_hi, znorm_lo);

  // 4) g stats, then normalize+relu+transpose g -> gT[b][n][128]
  stats_g<<<dim3(2048), 256, 0, stream>>>(z_all, statsg);
  norm_transpose_g<<<dim3(64, 16), 256, 0, stream>>>(z_all, statsg, gT);

  // 5) f = theta . phi^T, split 3-pass, K=4096 in 32 chunks (512 blocks, 2/CU)
  gemm_tn<3, false><<<dim3(1, 1, 512), 256, 0, stream>>>(
      znorm_hi, znorm_lo, znorm_hi + (long)128 * 4096, znorm_lo + (long)128 * 4096, fpart,
      4096, 4096, 128, 2, 32,
      128, (long)256 * 4096, 128, (long)256 * 4096, 16384, 524288);

  // 6) softmax rows -> attn bf16
  softmax_attn<<<dim3(2048), 64, 0, stream>>>(fpart, attn);

  // 7) y = attn . g, written scrambled-transposed (verified-consistent view)
  gemm_tn<1, true><<<dim3(1, 1, 512), 256, 0, stream>>>(
      attn, nullptr, gT, nullptr, y4T,
      128, 4096, 128, 2, 32,
      0, 16384, 128, (long)4096 * 128, 16384, (long)4096 * 128);

  // 8) final conv -> bf16 z2b [b][o][p]
  gemm_tn<1, true><<<dim3(32, 2, 16), 256, 0, stream>>>(
      w2h, nullptr, y4T, nullptr, z2b,
      128, 128, 4096, 2, 1,
      0, 0, 0, (long)4096 * 128, 0, (long)256 * 4096);

  // 9) instance-norm of z2 + residual x -> d_out fp32
  finalize<<<dim3(4096), 256, 0, stream>>>(z2b, x, (float*)d_out);
}

// Round 4
// 174.367 us; speedup vs baseline: 1.1557x; 1.0384x over previous
//
#include <hip/hip_runtime.h>

#define DEVINL __device__ __forceinline__

typedef __attribute__((ext_vector_type(8))) short bf8v;           // 8 bf16 bit-patterns (MFMA operand)
typedef __attribute__((ext_vector_type(4))) float f32x4;
typedef __attribute__((ext_vector_type(8))) unsigned short us8;
typedef __attribute__((ext_vector_type(4))) unsigned short us4;

DEVINL unsigned short f2bf(float f) {                 // round-to-nearest-even fp32->bf16
  unsigned int u = __builtin_bit_cast(unsigned int, f);
  u += 0x7fffu + ((u >> 16) & 1u);
  return (unsigned short)(u >> 16);
}
DEVINL unsigned short f2bf_trunc(float f) {           // truncate (for lo residuals)
  return (unsigned short)(__builtin_bit_cast(unsigned int, f) >> 16);
}
DEVINL float bf2f(unsigned short h) {
  unsigned int u = ((unsigned int)h) << 16;
  return __builtin_bit_cast(float, u);
}

// ------------------------------------------------------------------
// Fused projection, tile = M384 x N64, BK=32 (LDS 60KB -> 2 blocks/CU).
// theta/phi rows (0..255): 3-pass hi/lo split MFMA; g rows (256..383): 1-pass.
// Writes raw z as hi/lo bf16 split (reconstructable to ~1e-5 rel) and
// per-block partial (sum, sumsq) per row for instance-norm stats.
// 512 thr = 8 waves (4m x 2n); frag rows interleaved fr = mi*4+wm.
// ------------------------------------------------------------------
__global__ __launch_bounds__(512, 4)
void proj_gemm(const unsigned short* __restrict__ wall_hi,
               const unsigned short* __restrict__ wall_lo,
               const float* __restrict__ x,
               unsigned short* __restrict__ zr_hi, unsigned short* __restrict__ zr_lo,
               float* __restrict__ partials)
{
  __shared__ __align__(16) unsigned short As_hi[384 * 40];
  __shared__ __align__(16) unsigned short As_lo[256 * 40];
  __shared__ __align__(16) unsigned short Bs_hi[64 * 40];
  __shared__ __align__(16) unsigned short Bs_lo[64 * 40];

  const int t = threadIdx.x;
  const int lane = t & 63;
  const int wave = t >> 6;                 // 0..7
  const int wm = wave >> 1, wn = wave & 1; // 4 x 2
  const int lr = lane & 15, lk = lane >> 4;
  const int b = blockIdx.z;
  const int bx = blockIdx.x;
  const int nbase = bx * 64;
  const float* xs = x + (long)b * 256 * 4096;

  f32x4 acc[6][2];
#pragma unroll
  for (int i = 0; i < 6; ++i)
#pragma unroll
    for (int j = 0; j < 2; ++j) acc[i][j] = (f32x4)0.0f;

  for (int kt = 0; kt < 8; ++kt) {
    const int k0 = kt * 32;
    // A hi: 384 rows x 4 us8-chunks = 1536 -> 3/thread
#pragma unroll
    for (int i = 0; i < 3; ++i) {
      const int q = i * 512 + t;
      const int row = q >> 2, c = q & 3;
      *(us8*)&As_hi[row * 40 + c * 8] = *(const us8*)&wall_hi[(long)row * 256 + k0 + c * 8];
    }
    // A lo: 256 rows x 4 = 1024 -> 2/thread
#pragma unroll
    for (int i = 0; i < 2; ++i) {
      const int q = i * 512 + t;
      const int row = q >> 2, c = q & 3;
      *(us8*)&As_lo[row * 40 + c * 8] = *(const us8*)&wall_lo[(long)row * 256 + k0 + c * 8];
    }
    // B from fp32 x[c][n]: 32 c x 64 n; lane-major n -> coalesced
    const int nl = t & 63, cg = t >> 6;    // cg 0..7, 4 c each
    float xv[4];
#pragma unroll
    for (int i = 0; i < 4; ++i)
      xv[i] = xs[(long)(k0 + cg * 4 + i) * 4096 + nbase + nl];
    us4 h4, l4;
#pragma unroll
    for (int e = 0; e < 4; ++e) {
      const float v = xv[e];
      const unsigned short hb = f2bf(v);
      h4[e] = hb;
      l4[e] = f2bf_trunc(v - bf2f(hb));
    }
    *(us4*)&Bs_hi[nl * 40 + cg * 4] = h4;
    *(us4*)&Bs_lo[nl * 40 + cg * 4] = l4;
    __syncthreads();

    const int ko = lk * 8;
    bf8v bh[2], bl[2];
#pragma unroll
    for (int ni = 0; ni < 2; ++ni) {
      const int r = (wn * 32 + ni * 16 + lr) * 40 + ko;
      bh[ni] = *(const bf8v*)&Bs_hi[r];
      bl[ni] = *(const bf8v*)&Bs_lo[r];
    }
#pragma unroll
    for (int mi = 0; mi < 6; ++mi) {
      const int fr = mi * 4 + wm;          // frag row block 0..23
      const int r = (fr * 16 + lr) * 40 + ko;
      const bf8v ah = *(const bf8v*)&As_hi[r];
      if (fr < 16) {                        // theta/phi: 3-pass split
        const bf8v al = *(const bf8v*)&As_lo[r];
#pragma unroll
        for (int ni = 0; ni < 2; ++ni) {
          acc[mi][ni] = __builtin_amdgcn_mfma_f32_16x16x32_bf16(bh[ni], ah, acc[mi][ni], 0, 0, 0);
          acc[mi][ni] = __builtin_amdgcn_mfma_f32_16x16x32_bf16(bl[ni], ah, acc[mi][ni], 0, 0, 0);
          acc[mi][ni] = __builtin_amdgcn_mfma_f32_16x16x32_bf16(bh[ni], al, acc[mi][ni], 0, 0, 0);
        }
      } else {                              // g: 1-pass
#pragma unroll
        for (int ni = 0; ni < 2; ++ni)
          acc[mi][ni] = __builtin_amdgcn_mfma_f32_16x16x32_bf16(bh[ni], ah, acc[mi][ni], 0, 0, 0);
      }
    }
    __syncthreads();
  }

  // ---- partial stats: per row m, sum over this block's 64 n ----
  float* sbuf = (float*)As_hi;             // 24*16*8*2 floats = 24KB, alias
#pragma unroll
  for (int mi = 0; mi < 6; ++mi) {
    float s = 0.f, ss = 0.f;
#pragma unroll
    for (int ni = 0; ni < 2; ++ni)
#pragma unroll
      for (int r = 0; r < 4; ++r) {
        const float v = acc[mi][ni][r];
        s += v; ss += v * v;
      }
    const int fr = mi * 4 + wm;
    const int slot = ((fr * 16 + lr) * 8 + (wn * 4 + lk)) * 2;
    sbuf[slot] = s; sbuf[slot + 1] = ss;
  }
  __syncthreads();
  if (t < 384) {
    float s = 0.f, ss = 0.f;
#pragma unroll
    for (int w = 0; w < 8; ++w) {
      s += sbuf[(t * 8 + w) * 2];
      ss += sbuf[(t * 8 + w) * 2 + 1];
    }
    const long pidx = ((long)bx * 6144 + b * 384 + t) * 2;
    partials[pidx] = s; partials[pidx + 1] = ss;
  }

  // ---- C write: hi/lo split of raw z (swapped layout: lr->m, lk*4+r->n) ----
#pragma unroll
  for (int mi = 0; mi < 6; ++mi)
#pragma unroll
    for (int ni = 0; ni < 2; ++ni) {
      const int gm = (mi * 4 + wm) * 16 + lr;
      const int gn = nbase + wn * 32 + ni * 16 + lk * 4;
      const long o = ((long)b * 384 + gm) * 4096 + gn;
      us4 hv, lv;
#pragma unroll
      for (int r = 0; r < 4; ++r) {
        const float v = acc[mi][ni][r];
        const unsigned short h = f2bf(v);
        hv[r] = h;
        lv[r] = f2bf_trunc(v - bf2f(h));
      }
      *(us4*)&zr_hi[o] = hv;
      *(us4*)&zr_lo[o] = lv;
    }
}

// ------------------------------------------------------------------
// reduce 64 partial (s,ss) per row -> stats[row] = {rs, -mean*rs}
// ------------------------------------------------------------------
__global__ __launch_bounds__(256)
void stats_reduce(const float* __restrict__ partials, float* __restrict__ stats)
{
  const int row = blockIdx.x * 256 + threadIdx.x;   // [0, 6144)
  float s = 0.f, ss = 0.f;
#pragma unroll
  for (int k = 0; k < 64; ++k) {
    s += partials[((long)k * 6144 + row) * 2];
    ss += partials[((long)k * 6144 + row) * 2 + 1];
  }
  const float mean = s * (1.f / 4096.f);
  const float var = ss * (1.f / 4096.f) - mean * mean;
  const float rs = rsqrtf(fmaxf(var, 0.f) + 1e-5f);
  stats[row * 2] = rs;
  stats[row * 2 + 1] = -mean * rs;
}

// ------------------------------------------------------------------
// f = theta.phi^T with normalize+relu+re-split fused into LDS staging.
// 3-pass split MFMA, tile 128x128, BK=64, K-slice 128 per z1 (32 chunks).
// ------------------------------------------------------------------
__global__ __launch_bounds__(256, 4)
void fgemm_norm(const unsigned short* __restrict__ zr_hi, const unsigned short* __restrict__ zr_lo,
                const float* __restrict__ stats, float* __restrict__ fpart)
{
  __shared__ __align__(16) unsigned short As_hi[128 * 72];
  __shared__ __align__(16) unsigned short As_lo[128 * 72];
  __shared__ __align__(16) unsigned short Bs_hi[128 * 72];
  __shared__ __align__(16) unsigned short Bs_lo[128 * 72];

  const int t = threadIdx.x;
  const int lane = t & 63;
  const int wave = t >> 6;
  const int wm = wave >> 1, wn = wave & 1;
  const int lr = lane & 15, lk = lane >> 4;
  const int zb = blockIdx.z >> 5, z1 = blockIdx.z & 31;
  const int koff = z1 * 128;

  f32x4 acc[4][4];
#pragma unroll
  for (int i = 0; i < 4; ++i)
#pragma unroll
    for (int j = 0; j < 4; ++j) acc[i][j] = (f32x4)0.0f;

  for (int kt = 0; kt < 2; ++kt) {
    const int k0 = koff + kt * 64;
#pragma unroll
    for (int i = 0; i < 4; ++i) {
      const int q = i * 256 + t;
      const int row = q >> 3, c = q & 7;
      // A = theta (rows 0..127), B = phi (rows 128..255)
#pragma unroll
      for (int op = 0; op < 2; ++op) {
        const int grow = zb * 384 + op * 128 + row;
        const long g = (long)grow * 4096 + k0 + c * 8;
        const us8 h = *(const us8*)&zr_hi[g];
        const us8 l = *(const us8*)&zr_lo[g];
        const float rs = stats[grow * 2];
        const float nmrs = stats[grow * 2 + 1];
        us8 oh, ol;
#pragma unroll
        for (int e = 0; e < 8; ++e) {
          const float v = bf2f(h[e]) + bf2f(l[e]);
          const float nv = fmaxf(__builtin_fmaf(v, rs, nmrs), 0.f);
          const unsigned short hb = f2bf(nv);
          oh[e] = hb;
          ol[e] = f2bf_trunc(nv - bf2f(hb));
        }
        unsigned short* dh = op ? Bs_hi : As_hi;
        unsigned short* dl = op ? Bs_lo : As_lo;
        *(us8*)&dh[row * 72 + c * 8] = oh;
        *(us8*)&dl[row * 72 + c * 8] = ol;
      }
    }
    __syncthreads();
#pragma unroll
    for (int ks = 0; ks < 2; ++ks) {
      const int ko = ks * 32 + lk * 8;
      bf8v ah[4], bh[4], al[4], bl[4];
#pragma unroll
      for (int mi = 0; mi < 4; ++mi) {
        const int r = (wm * 64 + mi * 16 + lr) * 72 + ko;
        ah[mi] = *(const bf8v*)&As_hi[r];
        al[mi] = *(const bf8v*)&As_lo[r];
      }
#pragma unroll
      for (int ni = 0; ni < 4; ++ni) {
        const int r = (wn * 64 + ni * 16 + lr) * 72 + ko;
        bh[ni] = *(const bf8v*)&Bs_hi[r];
        bl[ni] = *(const bf8v*)&Bs_lo[r];
      }
#pragma unroll
      for (int mi = 0; mi < 4; ++mi)
#pragma unroll
        for (int ni = 0; ni < 4; ++ni) {
          acc[mi][ni] = __builtin_amdgcn_mfma_f32_16x16x32_bf16(bh[ni], ah[mi], acc[mi][ni], 0, 0, 0);
          acc[mi][ni] = __builtin_amdgcn_mfma_f32_16x16x32_bf16(bl[ni], ah[mi], acc[mi][ni], 0, 0, 0);
          acc[mi][ni] = __builtin_amdgcn_mfma_f32_16x16x32_bf16(bh[ni], al[mi], acc[mi][ni], 0, 0, 0);
        }
    }
    __syncthreads();
  }

  const long cOff = ((long)zb * 32 + z1) * 16384;
#pragma unroll
  for (int mi = 0; mi < 4; ++mi)
#pragma unroll
    for (int ni = 0; ni < 4; ++ni) {
      const int gm = wm * 64 + mi * 16 + lr;
      const int gn = wn * 64 + ni * 16 + lk * 4;
      *(f32x4*)&fpart[cOff + (long)gm * 128 + gn] = acc[mi][ni];
    }
}

// ------------------------------------------------------------------
// Generic TN GEMM (y / conv2), 1-pass bf16, tile 128x128, BK=64.
// ------------------------------------------------------------------
template<bool OUT_BF16>
__global__ __launch_bounds__(256, 2)
void gemm_tn(const unsigned short* __restrict__ Ah0, const unsigned short* __restrict__ Bh0,
             void* __restrict__ Cout,
             int lda, int ldb, int ldc, int ksteps, int z1count,
             long aS1, long aS2, long bS1, long bS2, long cS1, long cS2)
{
  __shared__ __align__(16) unsigned short As_hi[128 * 72];
  __shared__ __align__(16) unsigned short Bs_hi[128 * 72];

  const int t = threadIdx.x;
  const int lane = t & 63;
  const int wave = t >> 6;
  const int wm = wave >> 1, wn = wave & 1;
  const int lr = lane & 15, lk = lane >> 4;

  const int z = blockIdx.z;
  const int zb = z / z1count, z1 = z - zb * z1count;
  const unsigned short* Ah = Ah0 + zb * aS2 + z1 * aS1;
  const unsigned short* Bh = Bh0 + zb * bS2 + z1 * bS1;
  const long cOff = zb * cS2 + z1 * cS1;

  const int mbase = blockIdx.y * 128;
  const int nbase = blockIdx.x * 128;

  f32x4 acc[4][4];
#pragma unroll
  for (int i = 0; i < 4; ++i)
#pragma unroll
    for (int j = 0; j < 4; ++j) acc[i][j] = (f32x4)0.0f;

  for (int kt = 0; kt < ksteps; ++kt) {
    const int k0 = kt * 64;
#pragma unroll
    for (int i = 0; i < 4; ++i) {
      const int q = i * 256 + t;
      const int row = q >> 3, c = q & 7;
      const int lo = row * 72 + c * 8;
      *(us8*)&As_hi[lo] = *(const us8*)&Ah[(long)(mbase + row) * lda + k0 + c * 8];
      *(us8*)&Bs_hi[lo] = *(const us8*)&Bh[(long)(nbase + row) * ldb + k0 + c * 8];
    }
    __syncthreads();
#pragma unroll
    for (int ks = 0; ks < 2; ++ks) {
      const int ko = ks * 32 + lk * 8;
      bf8v ah[4], bh[4];
#pragma unroll
      for (int mi = 0; mi < 4; ++mi)
        ah[mi] = *(const bf8v*)&As_hi[(wm * 64 + mi * 16 + lr) * 72 + ko];
#pragma unroll
      for (int ni = 0; ni < 4; ++ni)
        bh[ni] = *(const bf8v*)&Bs_hi[(wn * 64 + ni * 16 + lr) * 72 + ko];
#pragma unroll
      for (int mi = 0; mi < 4; ++mi)
#pragma unroll
        for (int ni = 0; ni < 4; ++ni)
          acc[mi][ni] = __builtin_amdgcn_mfma_f32_16x16x32_bf16(bh[ni], ah[mi], acc[mi][ni], 0, 0, 0);
    }
    __syncthreads();
  }

#pragma unroll
  for (int mi = 0; mi < 4; ++mi)
#pragma unroll
    for (int ni = 0; ni < 4; ++ni) {
      const int gm = mbase + wm * 64 + mi * 16 + lr;
      const int gn = nbase + wn * 64 + ni * 16 + lk * 4;
      const f32x4 v = acc[mi][ni];
      if (OUT_BF16) {
        us4 o;
#pragma unroll
        for (int r = 0; r < 4; ++r) o[r] = f2bf(v[r]);
        *(us4*)&((unsigned short*)Cout)[cOff + (long)gm * ldc + gn] = o;
      } else {
        *(f32x4*)&((float*)Cout)[cOff + (long)gm * ldc + gn] = v;
      }
    }
}

// ------------------------------------------------------------------
// weights: wall rows [0..127]=theta, [128..255]=phi (hi+lo), [256..383]=g (hi);
// W2 -> bf16 [256][128]
// ------------------------------------------------------------------
__global__ __launch_bounds__(256)
void prep_weights(const float* __restrict__ g_w, const float* __restrict__ th_w,
                  const float* __restrict__ ph_w, const float* __restrict__ W_w,
                  unsigned short* __restrict__ wall_hi, unsigned short* __restrict__ wall_lo,
                  unsigned short* __restrict__ w2h)
{
  const int i = blockIdx.x * 256 + threadIdx.x;  // [0, 98304)
  float v;
  if (i < 32768) v = th_w[i];
  else if (i < 65536) v = ph_w[i - 32768];
  else v = g_w[i - 65536];
  const unsigned short h = f2bf(v);
  wall_hi[i] = h;
  if (i < 65536) wall_lo[i] = f2bf_trunc(v - bf2f(h));
  if (i < 32768) w2h[i] = f2bf(W_w[i]);
}

// ------------------------------------------------------------------
// normalize + relu + transpose g (from raw hi/lo split): -> gT [b][n][128]
// ------------------------------------------------------------------
__global__ __launch_bounds__(256)
void norm_transpose_g(const unsigned short* __restrict__ zr_hi,
                      const unsigned short* __restrict__ zr_lo,
                      const float* __restrict__ stats,
                      unsigned short* __restrict__ gT)
{
  __shared__ unsigned short T[64 * 136];
  const int b = blockIdx.y, n0 = blockIdx.x * 64;
  const int t = threadIdx.x;
  const int c = t >> 1, part = t & 1;
  const int grow = b * 384 + 256 + c;
  const float rs = stats[grow * 2];
  const float nmrs = stats[grow * 2 + 1];
  const long off = (long)grow * 4096 + n0 + part * 32;
#pragma unroll
  for (int j = 0; j < 8; ++j) {
    const us4 h = *(const us4*)&zr_hi[off + j * 4];
    const us4 l = *(const us4*)&zr_lo[off + j * 4];
#pragma unroll
    for (int e = 0; e < 4; ++e) {
      const float v = bf2f(h[e]) + bf2f(l[e]);
      const float nv = fmaxf(__builtin_fmaf(v, rs, nmrs), 0.f);
      T[(part * 32 + j * 4 + e) * 136 + c] = f2bf(nv);
    }
  }
  __syncthreads();
  const int nl = t >> 2, q = t & 3;
  const long obase = ((long)b * 4096 + n0 + nl) * 128 + q * 32;
#pragma unroll
  for (int k = 0; k < 4; ++k) {
    us8 o;
#pragma unroll
    for (int e = 0; e < 8; ++e) o[e] = T[nl * 136 + q * 32 + k * 8 + e];
    *(us8*)&gT[obase + k * 8] = o;
  }
}

// ------------------------------------------------------------------
// softmax over j: sums 32 deterministic K-split partials, writes attn bf16
// ------------------------------------------------------------------
__global__ __launch_bounds__(64)
void softmax_attn(const float* __restrict__ fpart, unsigned short* __restrict__ attn)
{
  const int row = blockIdx.x;            // b*128 + i
  const int b = row >> 7, i = row & 127;
  const int t = threadIdx.x;
  float v0 = 0.f, v1 = 0.f;
#pragma unroll
  for (int kc = 0; kc < 32; ++kc) {
    const float* p = fpart + ((long)(b * 32 + kc)) * 16384 + i * 128;
    v0 += p[t];
    v1 += p[t + 64];
  }
  float mx = fmaxf(v0, v1);
  for (int o = 32; o > 0; o >>= 1) mx = fmaxf(mx, __shfl_xor(mx, o));
  const float e0 = __expf(v0 - mx), e1 = __expf(v1 - mx);
  float s = e0 + e1;
  for (int o = 32; o > 0; o >>= 1) s += __shfl_xor(s, o);
  const float inv = 1.f / s;
  attn[(long)row * 128 + t] = f2bf(e0 * inv);
  attn[(long)row * 128 + t + 64] = f2bf(e1 * inv);
}

// ------------------------------------------------------------------
// final: instance-norm of bf16 z2 + residual x -> fp32 d_out
// ------------------------------------------------------------------
__global__ __launch_bounds__(256)
void finalize(const unsigned short* __restrict__ z2b, const float* __restrict__ x,
              float* __restrict__ out)
{
  const int row = blockIdx.x;            // b*256 + o
  const long base = (long)row * 4096;
  const int t = threadIdx.x;
  float v[16];
  float s = 0.f, ss = 0.f;
#pragma unroll
  for (int h = 0; h < 2; ++h) {
    us8 u = *(const us8*)&z2b[base + t * 16 + h * 8];
#pragma unroll
    for (int e = 0; e < 8; ++e) {
      const float f = bf2f(u[e]);
      v[h * 8 + e] = f;
      s += f; ss += f * f;
    }
  }
  __shared__ float r0[256], r1[256];
  r0[t] = s; r1[t] = ss;
  __syncthreads();
  for (int o = 128; o > 0; o >>= 1) {
    if (t < o) { r0[t] += r0[t + o]; r1[t] += r1[t + o]; }
    __syncthreads();
  }
  const float mean = r0[0] * (1.f / 4096.f);
  const float var = r1[0] * (1.f / 4096.f) - mean * mean;
  const float rs = rsqrtf(fmaxf(var, 0.f) + 1e-5f);
#pragma unroll
  for (int i = 0; i < 4; ++i) {
    f32x4 xr = *(const f32x4*)&x[base + t * 16 + i * 4];
    f32x4 o;
#pragma unroll
    for (int e = 0; e < 4; ++e) o[e] = (v[i * 4 + e] - mean) * rs + xr[e];
    *(f32x4*)&out[base + t * 16 + i * 4] = o;
  }
}

// ------------------------------------------------------------------
extern "C" void kernel_launch(void* const* d_in, const int* in_sizes, int n_in,
                              void* d_out, int out_size, void* d_ws, size_t ws_size,
                              hipStream_t stream)
{
  const float* x    = (const float*)d_in[0];
  const float* g_w  = (const float*)d_in[1];
  const float* th_w = (const float*)d_in[3];
  const float* ph_w = (const float*)d_in[5];
  const float* W_w  = (const float*)d_in[7];

  char* ws = (char*)d_ws;
  const size_t MB = 1024ull * 1024ull;
  if (ws_size < 186 * MB) return;

  // region map:
  // [0,48)    zr_hi  (raw z hi)      -> reused as z2b (32MB) after f/ntg done
  // [48,96)   zr_lo  (raw z lo)
  // [96,128)  fpart
  // [128,132) attn
  // [132,148) gT
  // [148,164) y4T
  // [164,167) partials (3MB)
  // [167,..)  stats + weights
  unsigned short* zr_hi    = (unsigned short*)(ws);
  unsigned short* zr_lo    = (unsigned short*)(ws + 48 * MB);
  float*          fpart    = (float*)(ws + 96 * MB);
  unsigned short* attn     = (unsigned short*)(ws + 128 * MB);
  unsigned short* gT       = (unsigned short*)(ws + 132 * MB);
  unsigned short* y4T      = (unsigned short*)(ws + 148 * MB);
  unsigned short* z2b      = (unsigned short*)(ws);             // reuse zr_hi
  float*          partials = (float*)(ws + 164 * MB);
  float*          stats    = (float*)(ws + 167 * MB);
  unsigned short* wall_hi  = (unsigned short*)(ws + 168 * MB);
  unsigned short* wall_lo  = (unsigned short*)(ws + 168 * MB + 256 * 1024);
  unsigned short* w2h      = (unsigned short*)(ws + 168 * MB + 512 * 1024);

  // 1) weight prep
  prep_weights<<<dim3(384), 256, 0, stream>>>(g_w, th_w, ph_w, W_w, wall_hi, wall_lo, w2h);

  // 2) projection (x read once per block-col; raw z split + stat partials)
  proj_gemm<<<dim3(64, 1, 16), 512, 0, stream>>>(wall_hi, wall_lo, x, zr_hi, zr_lo, partials);

  // 3) instance-norm stats
  stats_reduce<<<dim3(24), 256, 0, stream>>>(partials, stats);

  // 4) g: normalize+relu+transpose -> gT[b][n][128]
  norm_transpose_g<<<dim3(64, 16), 256, 0, stream>>>(zr_hi, zr_lo, stats, gT);

  // 5) f = theta.phi^T (normalize fused in staging), K=4096 in 32 chunks
  fgemm_norm<<<dim3(1, 1, 512), 256, 0, stream>>>(zr_hi, zr_lo, stats, fpart);

  // 6) softmax rows -> attn bf16
  softmax_attn<<<dim3(2048), 64, 0, stream>>>(fpart, attn);

  // 7) y = attn . g, written scrambled-transposed y4T[b][p][c]
  gemm_tn<true><<<dim3(1, 1, 512), 256, 0, stream>>>(
      attn, gT, y4T,
      128, 4096, 128, 2, 32,
      0, 16384, 128, (long)4096 * 128, 16384, (long)4096 * 128);

  // 8) final conv -> bf16 z2b [b][o][p]  (overwrites zr_hi region)
  gemm_tn<true><<<dim3(32, 2, 16), 256, 0, stream>>>(
      w2h, y4T, z2b,
      128, 128, 4096, 2, 1,
      0, 0, 0, (long)4096 * 128, 0, (long)256 * 4096);

  // 9) instance-norm of z2 + residual x -> d_out fp32
  finalize<<<dim3(4096), 256, 0, stream>>>(z2b, x, (float*)d_out);
}

// Round 5
// 160.782 us; speedup vs baseline: 1.2534x; 1.0845x over previous
//
#include <hip/hip_runtime.h>

#define DEVINL __device__ __forceinline__

typedef __attribute__((ext_vector_type(8))) short bf8v;           // 8 bf16 bit-patterns (MFMA operand)
typedef __attribute__((ext_vector_type(4))) float f32x4;
typedef __attribute__((ext_vector_type(8))) unsigned short us8;
typedef __attribute__((ext_vector_type(4))) unsigned short us4;

DEVINL unsigned short f2bf(float f) {                 // round-to-nearest-even fp32->bf16
  unsigned int u = __builtin_bit_cast(unsigned int, f);
  u += 0x7fffu + ((u >> 16) & 1u);
  return (unsigned short)(u >> 16);
}
DEVINL unsigned short f2bf_trunc(float f) {           // truncate (for lo residuals)
  return (unsigned short)(__builtin_bit_cast(unsigned int, f) >> 16);
}
DEVINL float bf2f(unsigned short h) {
  unsigned int u = ((unsigned int)h) << 16;
  return __builtin_bit_cast(float, u);
}

// ------------------------------------------------------------------
// Fused projection, tile = M384 x N128, BK=64 (LDS 129KB, 1 block/CU,
// 8 waves). theta/phi rows (0..255): 3-pass hi/lo split; g rows: 1-pass.
// B (x) is reg-staged one K-tile ahead: loads for kt+1 issued right
// after the stage barrier so HBM latency hides under the MFMA phase.
// Outputs: raw z hi/lo bf16 split (lo only for theta/phi rows) and
// per-block partial (sum,sumsq) per row for instance-norm stats.
// ------------------------------------------------------------------
__global__ __launch_bounds__(512, 2)
void proj_gemm(const unsigned short* __restrict__ wall_hi,
               const unsigned short* __restrict__ wall_lo,
               const float* __restrict__ x,
               unsigned short* __restrict__ zr_hi, unsigned short* __restrict__ zr_lo,
               float* __restrict__ partials)
{
  __shared__ __align__(16) unsigned short As_hi[384 * 72];
  __shared__ __align__(16) unsigned short As_lo[256 * 72];
  __shared__ __align__(16) unsigned short Bs_hi[128 * 72];
  __shared__ __align__(16) unsigned short Bs_lo[128 * 72];

  const int t = threadIdx.x;
  const int lane = t & 63;
  const int wave = t >> 6;                 // 0..7
  const int wm = wave >> 1, wn = wave & 1; // 4 x 2
  const int lr = lane & 15, lk = lane >> 4;
  const int b = blockIdx.z;
  const int bx = blockIdx.x;
  const int nbase = bx * 128;
  const float* xs = x + (long)b * 256 * 4096;

  const int nl = t & 127, cg = t >> 7;     // B staging: lane-per-n, 4 c-groups x 16
  float xv[16];

  f32x4 acc[6][4];
#pragma unroll
  for (int i = 0; i < 6; ++i)
#pragma unroll
    for (int j = 0; j < 4; ++j) acc[i][j] = (f32x4)0.0f;

  // prefetch B for kt=0
#pragma unroll
  for (int i = 0; i < 16; ++i)
    xv[i] = xs[(long)(cg * 16 + i) * 4096 + nbase + nl];

  for (int kt = 0; kt < 4; ++kt) {
    const int k0 = kt * 64;
    // A hi: 384 rows x 8 us8-chunks = 3072 -> 6/thread
#pragma unroll
    for (int i = 0; i < 6; ++i) {
      const int q = i * 512 + t;
      const int row = q >> 3, c = q & 7;
      *(us8*)&As_hi[row * 72 + c * 8] = *(const us8*)&wall_hi[(long)row * 256 + k0 + c * 8];
    }
    // A lo: 256 rows x 8 = 2048 -> 4/thread
#pragma unroll
    for (int i = 0; i < 4; ++i) {
      const int q = i * 512 + t;
      const int row = q >> 3, c = q & 7;
      *(us8*)&As_lo[row * 72 + c * 8] = *(const us8*)&wall_lo[(long)row * 256 + k0 + c * 8];
    }
    // B convert+split from prefetched regs
#pragma unroll
    for (int ch = 0; ch < 2; ++ch) {
      us8 h8, l8;
#pragma unroll
      for (int e = 0; e < 8; ++e) {
        const float v = xv[ch * 8 + e];
        const unsigned short hb = f2bf(v);
        h8[e] = hb;
        l8[e] = f2bf_trunc(v - bf2f(hb));
      }
      *(us8*)&Bs_hi[nl * 72 + cg * 16 + ch * 8] = h8;
      *(us8*)&Bs_lo[nl * 72 + cg * 16 + ch * 8] = l8;
    }
    __syncthreads();

    // prefetch B for kt+1 (in flight during MFMA phase)
    if (kt < 3) {
      const int kn = (kt + 1) * 64;
#pragma unroll
      for (int i = 0; i < 16; ++i)
        xv[i] = xs[(long)(kn + cg * 16 + i) * 4096 + nbase + nl];
    }

#pragma unroll
    for (int ks = 0; ks < 2; ++ks) {
      const int ko = ks * 32 + lk * 8;
      bf8v bh[4], bl[4];
#pragma unroll
      for (int ni = 0; ni < 4; ++ni) {
        const int r = (wn * 64 + ni * 16 + lr) * 72 + ko;
        bh[ni] = *(const bf8v*)&Bs_hi[r];
        bl[ni] = *(const bf8v*)&Bs_lo[r];
      }
#pragma unroll
      for (int mi = 0; mi < 6; ++mi) {
        const int fr = mi * 4 + wm;        // frag row block 0..23
        const int r = (fr * 16 + lr) * 72 + ko;
        const bf8v ah = *(const bf8v*)&As_hi[r];
        if (fr < 16) {                      // theta/phi: 3-pass split
          const bf8v al = *(const bf8v*)&As_lo[r];
#pragma unroll
          for (int ni = 0; ni < 4; ++ni) {
            acc[mi][ni] = __builtin_amdgcn_mfma_f32_16x16x32_bf16(bh[ni], ah, acc[mi][ni], 0, 0, 0);
            acc[mi][ni] = __builtin_amdgcn_mfma_f32_16x16x32_bf16(bl[ni], ah, acc[mi][ni], 0, 0, 0);
            acc[mi][ni] = __builtin_amdgcn_mfma_f32_16x16x32_bf16(bh[ni], al, acc[mi][ni], 0, 0, 0);
          }
        } else {                            // g: 1-pass
#pragma unroll
          for (int ni = 0; ni < 4; ++ni)
            acc[mi][ni] = __builtin_amdgcn_mfma_f32_16x16x32_bf16(bh[ni], ah, acc[mi][ni], 0, 0, 0);
        }
      }
    }
    __syncthreads();
  }

  // ---- partial stats: per row m, sum over this block's 128 n ----
  float* sbuf = (float*)As_hi;             // 384*8*2 floats = 24KB alias
#pragma unroll
  for (int mi = 0; mi < 6; ++mi) {
    float s = 0.f, ss = 0.f;
#pragma unroll
    for (int ni = 0; ni < 4; ++ni)
#pragma unroll
      for (int r = 0; r < 4; ++r) {
        const float v = acc[mi][ni][r];
        s += v; ss += v * v;
      }
    const int fr = mi * 4 + wm;
    const int slot = ((fr * 16 + lr) * 8 + (wn * 4 + lk)) * 2;
    sbuf[slot] = s; sbuf[slot + 1] = ss;
  }
  __syncthreads();
  if (t < 384) {
    float s = 0.f, ss = 0.f;
#pragma unroll
    for (int w = 0; w < 8; ++w) {
      s += sbuf[(t * 8 + w) * 2];
      ss += sbuf[(t * 8 + w) * 2 + 1];
    }
    const long pidx = ((long)bx * 6144 + b * 384 + t) * 2;
    partials[pidx] = s; partials[pidx + 1] = ss;
  }

  // ---- C write: hi/lo split of raw z (lo only for theta/phi rows) ----
#pragma unroll
  for (int mi = 0; mi < 6; ++mi)
#pragma unroll
    for (int ni = 0; ni < 4; ++ni) {
      const int gm = (mi * 4 + wm) * 16 + lr;
      const int gn = nbase + wn * 64 + ni * 16 + lk * 4;
      const long o = ((long)b * 384 + gm) * 4096 + gn;
      us4 hv, lv;
#pragma unroll
      for (int r = 0; r < 4; ++r) {
        const float v = acc[mi][ni][r];
        const unsigned short h = f2bf(v);
        hv[r] = h;
        lv[r] = f2bf_trunc(v - bf2f(h));
      }
      *(us4*)&zr_hi[o] = hv;
      if (gm < 256) *(us4*)&zr_lo[o] = lv;
    }
}

// ------------------------------------------------------------------
// reduce 32 partial (s,ss) per row -> stats[row] = {rs, -mean*rs}
// ------------------------------------------------------------------
__global__ __launch_bounds__(256)
void stats_reduce(const float* __restrict__ partials, float* __restrict__ stats)
{
  const int row = blockIdx.x * 256 + threadIdx.x;   // [0, 6144)
  float s = 0.f, ss = 0.f;
#pragma unroll
  for (int k = 0; k < 32; ++k) {
    s += partials[((long)k * 6144 + row) * 2];
    ss += partials[((long)k * 6144 + row) * 2 + 1];
  }
  const float mean = s * (1.f / 4096.f);
  const float var = ss * (1.f / 4096.f) - mean * mean;
  const float rs = rsqrtf(fmaxf(var, 0.f) + 1e-5f);
  stats[row * 2] = rs;
  stats[row * 2 + 1] = -mean * rs;
}

// ------------------------------------------------------------------
// f = theta.phi^T with normalize+relu+re-split fused into LDS staging.
// 3-pass split MFMA, tile 128x128, BK=64, K-slice 128 per z1 (32 chunks).
// ------------------------------------------------------------------
__global__ __launch_bounds__(256, 4)
void fgemm_norm(const unsigned short* __restrict__ zr_hi, const unsigned short* __restrict__ zr_lo,
                const float* __restrict__ stats, float* __restrict__ fpart)
{
  __shared__ __align__(16) unsigned short As_hi[128 * 72];
  __shared__ __align__(16) unsigned short As_lo[128 * 72];
  __shared__ __align__(16) unsigned short Bs_hi[128 * 72];
  __shared__ __align__(16) unsigned short Bs_lo[128 * 72];

  const int t = threadIdx.x;
  const int lane = t & 63;
  const int wave = t >> 6;
  const int wm = wave >> 1, wn = wave & 1;
  const int lr = lane & 15, lk = lane >> 4;
  const int zb = blockIdx.z >> 5, z1 = blockIdx.z & 31;
  const int koff = z1 * 128;

  f32x4 acc[4][4];
#pragma unroll
  for (int i = 0; i < 4; ++i)
#pragma unroll
    for (int j = 0; j < 4; ++j) acc[i][j] = (f32x4)0.0f;

  for (int kt = 0; kt < 2; ++kt) {
    const int k0 = koff + kt * 64;
#pragma unroll
    for (int i = 0; i < 4; ++i) {
      const int q = i * 256 + t;
      const int row = q >> 3, c = q & 7;
      // A = theta (rows 0..127), B = phi (rows 128..255)
#pragma unroll
      for (int op = 0; op < 2; ++op) {
        const int grow = zb * 384 + op * 128 + row;
        const long g = (long)grow * 4096 + k0 + c * 8;
        const us8 h = *(const us8*)&zr_hi[g];
        const us8 l = *(const us8*)&zr_lo[g];
        const float rs = stats[grow * 2];
        const float nmrs = stats[grow * 2 + 1];
        us8 oh, ol;
#pragma unroll
        for (int e = 0; e < 8; ++e) {
          const float v = bf2f(h[e]) + bf2f(l[e]);
          const float nv = fmaxf(__builtin_fmaf(v, rs, nmrs), 0.f);
          const unsigned short hb = f2bf(nv);
          oh[e] = hb;
          ol[e] = f2bf_trunc(nv - bf2f(hb));
        }
        unsigned short* dh = op ? Bs_hi : As_hi;
        unsigned short* dl = op ? Bs_lo : As_lo;
        *(us8*)&dh[row * 72 + c * 8] = oh;
        *(us8*)&dl[row * 72 + c * 8] = ol;
      }
    }
    __syncthreads();
#pragma unroll
    for (int ks = 0; ks < 2; ++ks) {
      const int ko = ks * 32 + lk * 8;
      bf8v ah[4], bh[4], al[4], bl[4];
#pragma unroll
      for (int mi = 0; mi < 4; ++mi) {
        const int r = (wm * 64 + mi * 16 + lr) * 72 + ko;
        ah[mi] = *(const bf8v*)&As_hi[r];
        al[mi] = *(const bf8v*)&As_lo[r];
      }
#pragma unroll
      for (int ni = 0; ni < 4; ++ni) {
        const int r = (wn * 64 + ni * 16 + lr) * 72 + ko;
        bh[ni] = *(const bf8v*)&Bs_hi[r];
        bl[ni] = *(const bf8v*)&Bs_lo[r];
      }
#pragma unroll
      for (int mi = 0; mi < 4; ++mi)
#pragma unroll
        for (int ni = 0; ni < 4; ++ni) {
          acc[mi][ni] = __builtin_amdgcn_mfma_f32_16x16x32_bf16(bh[ni], ah[mi], acc[mi][ni], 0, 0, 0);
          acc[mi][ni] = __builtin_amdgcn_mfma_f32_16x16x32_bf16(bl[ni], ah[mi], acc[mi][ni], 0, 0, 0);
          acc[mi][ni] = __builtin_amdgcn_mfma_f32_16x16x32_bf16(bh[ni], al[mi], acc[mi][ni], 0, 0, 0);
        }
    }
    __syncthreads();
  }

  const long cOff = ((long)zb * 32 + z1) * 16384;
#pragma unroll
  for (int mi = 0; mi < 4; ++mi)
#pragma unroll
    for (int ni = 0; ni < 4; ++ni) {
      const int gm = wm * 64 + mi * 16 + lr;
      const int gn = wn * 64 + ni * 16 + lk * 4;
      *(f32x4*)&fpart[cOff + (long)gm * 128 + gn] = acc[mi][ni];
    }
}

// ------------------------------------------------------------------
// y GEMM: tile 128x128, BK=64, 1-pass bf16, bf16 out.
// ------------------------------------------------------------------
__global__ __launch_bounds__(256, 2)
void gemm_y(const unsigned short* __restrict__ Ah0, const unsigned short* __restrict__ Bh0,
            unsigned short* __restrict__ Cout,
            int lda, int ldb, int ldc, int ksteps, int z1count,
            long aS1, long aS2, long bS1, long bS2, long cS1, long cS2)
{
  __shared__ __align__(16) unsigned short As_hi[128 * 72];
  __shared__ __align__(16) unsigned short Bs_hi[128 * 72];

  const int t = threadIdx.x;
  const int lane = t & 63;
  const int wave = t >> 6;
  const int wm = wave >> 1, wn = wave & 1;
  const int lr = lane & 15, lk = lane >> 4;

  const int z = blockIdx.z;
  const int zb = z / z1count, z1 = z - zb * z1count;
  const unsigned short* Ah = Ah0 + zb * aS2 + z1 * aS1;
  const unsigned short* Bh = Bh0 + zb * bS2 + z1 * bS1;
  const long cOff = zb * cS2 + z1 * cS1;

  f32x4 acc[4][4];
#pragma unroll
  for (int i = 0; i < 4; ++i)
#pragma unroll
    for (int j = 0; j < 4; ++j) acc[i][j] = (f32x4)0.0f;

  for (int kt = 0; kt < ksteps; ++kt) {
    const int k0 = kt * 64;
#pragma unroll
    for (int i = 0; i < 4; ++i) {
      const int q = i * 256 + t;
      const int row = q >> 3, c = q & 7;
      const int lo = row * 72 + c * 8;
      *(us8*)&As_hi[lo] = *(const us8*)&Ah[(long)row * lda + k0 + c * 8];
      *(us8*)&Bs_hi[lo] = *(const us8*)&Bh[(long)row * ldb + k0 + c * 8];
    }
    __syncthreads();
#pragma unroll
    for (int ks = 0; ks < 2; ++ks) {
      const int ko = ks * 32 + lk * 8;
      bf8v ah[4], bh[4];
#pragma unroll
      for (int mi = 0; mi < 4; ++mi)
        ah[mi] = *(const bf8v*)&As_hi[(wm * 64 + mi * 16 + lr) * 72 + ko];
#pragma unroll
      for (int ni = 0; ni < 4; ++ni)
        bh[ni] = *(const bf8v*)&Bs_hi[(wn * 64 + ni * 16 + lr) * 72 + ko];
#pragma unroll
      for (int mi = 0; mi < 4; ++mi)
#pragma unroll
        for (int ni = 0; ni < 4; ++ni)
          acc[mi][ni] = __builtin_amdgcn_mfma_f32_16x16x32_bf16(bh[ni], ah[mi], acc[mi][ni], 0, 0, 0);
    }
    __syncthreads();
  }

#pragma unroll
  for (int mi = 0; mi < 4; ++mi)
#pragma unroll
    for (int ni = 0; ni < 4; ++ni) {
      const int gm = wm * 64 + mi * 16 + lr;
      const int gn = wn * 64 + ni * 16 + lk * 4;
      const f32x4 v = acc[mi][ni];
      us4 o;
#pragma unroll
      for (int r = 0; r < 4; ++r) o[r] = f2bf(v[r]);
      *(us4*)&Cout[cOff + (long)gm * ldc + gn] = o;
    }
}

// ------------------------------------------------------------------
// conv2: z2[b][o][p] = sum_c w2h[o,c]*y4T[b][p][c].  Full M=256 per
// block (y4T read once), N=128 p-tile, K=128 (BK=64).  55KB LDS.
// ------------------------------------------------------------------
__global__ __launch_bounds__(256, 2)
void conv2_gemm(const unsigned short* __restrict__ w2h,
                const unsigned short* __restrict__ y4T,
                unsigned short* __restrict__ z2b)
{
  __shared__ __align__(16) unsigned short As_hi[256 * 72];
  __shared__ __align__(16) unsigned short Bs_hi[128 * 72];

  const int t = threadIdx.x;
  const int lane = t & 63;
  const int wave = t >> 6;
  const int wm = wave >> 1, wn = wave & 1;
  const int lr = lane & 15, lk = lane >> 4;
  const int b = blockIdx.z;
  const int nbase = blockIdx.x * 128;
  const unsigned short* Bh = y4T + (long)b * 4096 * 128 + (long)nbase * 128;

  f32x4 acc[8][4];
#pragma unroll
  for (int i = 0; i < 8; ++i)
#pragma unroll
    for (int j = 0; j < 4; ++j) acc[i][j] = (f32x4)0.0f;

  for (int kt = 0; kt < 2; ++kt) {
    const int k0 = kt * 64;
#pragma unroll
    for (int i = 0; i < 8; ++i) {           // A: 256 rows x 8 chunks
      const int q = i * 256 + t;
      const int row = q >> 3, c = q & 7;
      *(us8*)&As_hi[row * 72 + c * 8] = *(const us8*)&w2h[(long)row * 128 + k0 + c * 8];
    }
#pragma unroll
    for (int i = 0; i < 4; ++i) {           // B: 128 rows x 8 chunks
      const int q = i * 256 + t;
      const int row = q >> 3, c = q & 7;
      *(us8*)&Bs_hi[row * 72 + c * 8] = *(const us8*)&Bh[(long)row * 128 + k0 + c * 8];
    }
    __syncthreads();
#pragma unroll
    for (int ks = 0; ks < 2; ++ks) {
      const int ko = ks * 32 + lk * 8;
      bf8v ah[8], bh[4];
#pragma unroll
      for (int mi = 0; mi < 8; ++mi)
        ah[mi] = *(const bf8v*)&As_hi[(wm * 128 + mi * 16 + lr) * 72 + ko];
#pragma unroll
      for (int ni = 0; ni < 4; ++ni)
        bh[ni] = *(const bf8v*)&Bs_hi[(wn * 64 + ni * 16 + lr) * 72 + ko];
#pragma unroll
      for (int mi = 0; mi < 8; ++mi)
#pragma unroll
        for (int ni = 0; ni < 4; ++ni)
          acc[mi][ni] = __builtin_amdgcn_mfma_f32_16x16x32_bf16(bh[ni], ah[mi], acc[mi][ni], 0, 0, 0);
    }
    __syncthreads();
  }

#pragma unroll
  for (int mi = 0; mi < 8; ++mi)
#pragma unroll
    for (int ni = 0; ni < 4; ++ni) {
      const int gm = wm * 128 + mi * 16 + lr;
      const int gn = nbase + wn * 64 + ni * 16 + lk * 4;
      const f32x4 v = acc[mi][ni];
      us4 o;
#pragma unroll
      for (int r = 0; r < 4; ++r) o[r] = f2bf(v[r]);
      *(us4*)&z2b[((long)b * 256 + gm) * 4096 + gn] = o;
    }
}

// ------------------------------------------------------------------
// weights: wall rows [0..127]=theta, [128..255]=phi (hi+lo), [256..383]=g (hi);
// W2 -> bf16 [256][128]
// ------------------------------------------------------------------
__global__ __launch_bounds__(256)
void prep_weights(const float* __restrict__ g_w, const float* __restrict__ th_w,
                  const float* __restrict__ ph_w, const float* __restrict__ W_w,
                  unsigned short* __restrict__ wall_hi, unsigned short* __restrict__ wall_lo,
                  unsigned short* __restrict__ w2h)
{
  const int i = blockIdx.x * 256 + threadIdx.x;  // [0, 98304)
  float v;
  if (i < 32768) v = th_w[i];
  else if (i < 65536) v = ph_w[i - 32768];
  else v = g_w[i - 65536];
  const unsigned short h = f2bf(v);
  wall_hi[i] = h;
  if (i < 65536) wall_lo[i] = f2bf_trunc(v - bf2f(h));
  if (i < 32768) w2h[i] = f2bf(W_w[i]);
}

// ------------------------------------------------------------------
// normalize + relu + transpose g (hi only): -> gT [b][n][128] bf16
// ------------------------------------------------------------------
__global__ __launch_bounds__(256)
void norm_transpose_g(const unsigned short* __restrict__ zr_hi,
                      const float* __restrict__ stats,
                      unsigned short* __restrict__ gT)
{
  __shared__ unsigned short T[64 * 136];
  const int b = blockIdx.y, n0 = blockIdx.x * 64;
  const int t = threadIdx.x;
  const int c = t >> 1, part = t & 1;
  const int grow = b * 384 + 256 + c;
  const float rs = stats[grow * 2];
  const float nmrs = stats[grow * 2 + 1];
  const long off = (long)grow * 4096 + n0 + part * 32;
#pragma unroll
  for (int j = 0; j < 4; ++j) {
    const us8 h = *(const us8*)&zr_hi[off + j * 8];
#pragma unroll
    for (int e = 0; e < 8; ++e) {
      const float v = bf2f(h[e]);
      const float nv = fmaxf(__builtin_fmaf(v, rs, nmrs), 0.f);
      T[(part * 32 + j * 8 + e) * 136 + c] = f2bf(nv);
    }
  }
  __syncthreads();
  const int nl = t >> 2, q = t & 3;
  const long obase = ((long)b * 4096 + n0 + nl) * 128 + q * 32;
#pragma unroll
  for (int k = 0; k < 4; ++k) {
    us8 o;
#pragma unroll
    for (int e = 0; e < 8; ++e) o[e] = T[nl * 136 + q * 32 + k * 8 + e];
    *(us8*)&gT[obase + k * 8] = o;
  }
}

// ------------------------------------------------------------------
// softmax over j: sums 32 deterministic K-split partials, writes attn bf16
// ------------------------------------------------------------------
__global__ __launch_bounds__(64)
void softmax_attn(const float* __restrict__ fpart, unsigned short* __restrict__ attn)
{
  const int row = blockIdx.x;            // b*128 + i
  const int b = row >> 7, i = row & 127;
  const int t = threadIdx.x;
  float v0 = 0.f, v1 = 0.f;
#pragma unroll
  for (int kc = 0; kc < 32; ++kc) {
    const float* p = fpart + ((long)(b * 32 + kc)) * 16384 + i * 128;
    v0 += p[t];
    v1 += p[t + 64];
  }
  float mx = fmaxf(v0, v1);
  for (int o = 32; o > 0; o >>= 1) mx = fmaxf(mx, __shfl_xor(mx, o));
  const float e0 = __expf(v0 - mx), e1 = __expf(v1 - mx);
  float s = e0 + e1;
  for (int o = 32; o > 0; o >>= 1) s += __shfl_xor(s, o);
  const float inv = 1.f / s;
  attn[(long)row * 128 + t] = f2bf(e0 * inv);
  attn[(long)row * 128 + t + 64] = f2bf(e1 * inv);
}

// ------------------------------------------------------------------
// final: instance-norm of bf16 z2 + residual x -> fp32 d_out
// ------------------------------------------------------------------
__global__ __launch_bounds__(256)
void finalize(const unsigned short* __restrict__ z2b, const float* __restrict__ x,
              float* __restrict__ out)
{
  const int row = blockIdx.x;            // b*256 + o
  const long base = (long)row * 4096;
  const int t = threadIdx.x;
  float v[16];
  float s = 0.f, ss = 0.f;
#pragma unroll
  for (int h = 0; h < 2; ++h) {
    us8 u = *(const us8*)&z2b[base + t * 16 + h * 8];
#pragma unroll
    for (int e = 0; e < 8; ++e) {
      const float f = bf2f(u[e]);
      v[h * 8 + e] = f;
      s += f; ss += f * f;
    }
  }
  __shared__ float r0[256], r1[256];
  r0[t] = s; r1[t] = ss;
  __syncthreads();
  for (int o = 128; o > 0; o >>= 1) {
    if (t < o) { r0[t] += r0[t + o]; r1[t] += r1[t + o]; }
    __syncthreads();
  }
  const float mean = r0[0] * (1.f / 4096.f);
  const float var = r1[0] * (1.f / 4096.f) - mean * mean;
  const float rs = rsqrtf(fmaxf(var, 0.f) + 1e-5f);
#pragma unroll
  for (int i = 0; i < 4; ++i) {
    f32x4 xr = *(const f32x4*)&x[base + t * 16 + i * 4];
    f32x4 o;
#pragma unroll
    for (int e = 0; e < 4; ++e) o[e] = (v[i * 4 + e] - mean) * rs + xr[e];
    *(f32x4*)&out[base + t * 16 + i * 4] = o;
  }
}

// ------------------------------------------------------------------
extern "C" void kernel_launch(void* const* d_in, const int* in_sizes, int n_in,
                              void* d_out, int out_size, void* d_ws, size_t ws_size,
                              hipStream_t stream)
{
  const float* x    = (const float*)d_in[0];
  const float* g_w  = (const float*)d_in[1];
  const float* th_w = (const float*)d_in[3];
  const float* ph_w = (const float*)d_in[5];
  const float* W_w  = (const float*)d_in[7];

  char* ws = (char*)d_ws;
  const size_t MB = 1024ull * 1024ull;
  if (ws_size < 186 * MB) return;

  // region map:
  // [0,48)    zr_hi (raw z hi)   -> reused as z2b (32MB) after f/ntg done
  // [48,96)   zr_lo (raw z lo; only rows<256 per b written)
  // [96,128)  fpart
  // [128,132) attn
  // [132,148) gT
  // [148,164) y4T
  // [164,167) partials
  // [167,..)  stats + weights
  unsigned short* zr_hi    = (unsigned short*)(ws);
  unsigned short* zr_lo    = (unsigned short*)(ws + 48 * MB);
  float*          fpart    = (float*)(ws + 96 * MB);
  unsigned short* attn     = (unsigned short*)(ws + 128 * MB);
  unsigned short* gT       = (unsigned short*)(ws + 132 * MB);
  unsigned short* y4T      = (unsigned short*)(ws + 148 * MB);
  unsigned short* z2b      = (unsigned short*)(ws);             // reuse zr_hi
  float*          partials = (float*)(ws + 164 * MB);
  float*          stats    = (float*)(ws + 167 * MB);
  unsigned short* wall_hi  = (unsigned short*)(ws + 168 * MB);
  unsigned short* wall_lo  = (unsigned short*)(ws + 168 * MB + 256 * 1024);
  unsigned short* w2h      = (unsigned short*)(ws + 168 * MB + 512 * 1024);

  // 1) weight prep
  prep_weights<<<dim3(384), 256, 0, stream>>>(g_w, th_w, ph_w, W_w, wall_hi, wall_lo, w2h);

  // 2) projection (reg-prefetched B; raw z split + stat partials)
  proj_gemm<<<dim3(32, 1, 16), 512, 0, stream>>>(wall_hi, wall_lo, x, zr_hi, zr_lo, partials);

  // 3) instance-norm stats
  stats_reduce<<<dim3(24), 256, 0, stream>>>(partials, stats);

  // 4) g: normalize+relu+transpose (hi only) -> gT[b][n][128]
  norm_transpose_g<<<dim3(64, 16), 256, 0, stream>>>(zr_hi, stats, gT);

  // 5) f = theta.phi^T (normalize fused in staging), K=4096 in 32 chunks
  fgemm_norm<<<dim3(1, 1, 512), 256, 0, stream>>>(zr_hi, zr_lo, stats, fpart);

  // 6) softmax rows -> attn bf16
  softmax_attn<<<dim3(2048), 64, 0, stream>>>(fpart, attn);

  // 7) y = attn . g, written scrambled-transposed y4T[b][p][c]
  gemm_y<<<dim3(1, 1, 512), 256, 0, stream>>>(
      attn, gT, y4T,
      128, 4096, 128, 2, 32,
      0, 16384, 128, (long)4096 * 128, 16384, (long)4096 * 128);

  // 8) final conv -> bf16 z2b [b][o][p]  (y4T read once; overwrites zr_hi)
  conv2_gemm<<<dim3(32, 1, 16), 256, 0, stream>>>(w2h, y4T, z2b);

  // 9) instance-norm of z2 + residual x -> d_out fp32
  finalize<<<dim3(4096), 256, 0, stream>>>(z2b, x, (float*)d_out);
}